// Round 8
// baseline (511.859 us; speedup 1.0000x reference)
//
#include <hip/hip_runtime.h>
#include <math.h>

typedef __attribute__((ext_vector_type(8))) short short8;   // 8 bf16
typedef __attribute__((ext_vector_type(4))) short short4v;  // 4 bf16
typedef __attribute__((ext_vector_type(4))) float f32x4;
typedef unsigned int u32;

constexpr int Bsz = 10;
constexpr int Dm  = 256;
constexpr int Hh  = 8;
constexpr int Tt  = 1600;
constexpr int FFd = 2048;
constexpr int Tkv = 802;   // 1 null + 801 compressed
constexpr int JCH = 8;     // j-splits for kv reduction
constexpr size_t Fsz  = (size_t)Bsz * Tt * Dm;    // 4,096,000
constexpr size_t PAD  = 65536;
constexpr size_t KVsz = (size_t)Bsz * Tkv * Dm;   // 2,053,120
constexpr size_t FHsz = (size_t)Bsz * Tt * FFd;   // 32,768,000
constexpr size_t WBsz = 2621440;                  // all weights, bf16

// Static device scratch; referenced ONLY from device code.
__device__ float g_x[Fsz];                        // residual stream fp32
__device__ float g_qk[Fsz];                       // FF q0 out (LN2 d1)
__device__ float g_t[Fsz];                        // Wo out / FF q1 (LN2 d2)
__device__ float g_kc[KVsz];                      // compressed K
__device__ float g_vc[KVsz];                      // compressed V
__device__ float g_kvm[(size_t)Bsz * Hh * 32 * 32];
__device__ float g_kvp[(size_t)JCH * Bsz * Hh * 32 * 32];
__device__ float g_pos[Fsz];                      // transposed pos fp32
__device__ unsigned short g_xb[Fsz + PAD];        // bf16 shadow of x
__device__ unsigned short g_qkb[Fsz + PAD];       // bf16 x+pos
__device__ unsigned short g_tb[Fsz + PAD];        // bf16 k projection
__device__ unsigned short g_qb[Fsz + PAD];        // bf16 q projection
// v-proj scratch early in layer; FF quarters 2/3 reuse it as TWO f32 buffers.
__device__ __attribute__((aligned(16))) unsigned short g_ffh[FHsz + PAD];
__device__ unsigned short g_wb[WBsz];             // bf16 weights
__device__ unsigned short g_wo2[(size_t)Bsz * Dm * Dm];  // per-b fused kvm*Wo

__device__ __forceinline__ float* selbuf(int id) {
  switch (id) {
    case 0: return g_x;
    case 1: return g_qk;
    case 2: return g_t;
    case 3: return g_kc;
    case 4: return g_vc;
    case 5: return g_kvm;
    case 6: return (float*)g_ffh;
    default: return (float*)g_ffh + Fsz;
  }
}
__device__ __forceinline__ unsigned short* selbufb(int id) {
  switch (id) {
    case 0: return g_xb;
    case 1: return g_qkb;
    case 2: return g_tb;
    case 3: return g_ffh;
    default: return g_qb;
  }
}

// fp32 -> bf16 (RNE)
__device__ __forceinline__ unsigned short f2b(float x) {
  unsigned int u = __float_as_uint(x);
  u += 0x7FFFu + ((u >> 16) & 1u);
  return (unsigned short)(u >> 16);
}
__device__ __forceinline__ float b2f(unsigned short u) {
  return __uint_as_float(((unsigned int)u) << 16);
}

// ---------------------------------------------------------------------------
// ALL weight conversions in one dispatch. g_wb layout:
// [l0:Wk|Wq][l1:Wk|Wq] | Wv(l0,l1) | Wo(l0,l1) | W1(l0,l1) | W2(l0,l1)
__global__ __launch_bounds__(256) void wconv_all_k(
    const float* __restrict__ Wk, const float* __restrict__ Wq,
    const float* __restrict__ Wv, const float* __restrict__ Wo,
    const float* __restrict__ W1, const float* __restrict__ W2) {
  const int i = blockIdx.x * 256 + threadIdx.x;   // < 2,621,440
  float v;
  if (i < 262144) {
    const int l = i >> 17, r = i & 131071;
    v = (r < 65536) ? Wk[l * 65536 + r] : Wq[l * 65536 + (r - 65536)];
  } else if (i < 393216) {
    v = Wv[i - 262144];
  } else if (i < 524288) {
    v = Wo[i - 393216];
  } else if (i < 1572864) {
    v = W1[i - 524288];
  } else {
    v = W2[i - 1572864];
  }
  g_wb[i] = f2b(v);
}

// ---------------------------------------------------------------------------
// Fused input transpose + pos-add: src,pose [B,D,T] -> g_x, g_xb, g_pos,
// g_qkb = bf16(x+pos).
__global__ __launch_bounds__(256) void trans_in2_k(const float* __restrict__ src,
                                                   const float* __restrict__ pose) {
  __shared__ float ts[32][33];
  __shared__ float tp[32][33];
  const int tx = threadIdx.x & 31, ty = threadIdx.x >> 5;
  const int t0 = blockIdx.x * 32, d0 = blockIdx.y * 32, b = blockIdx.z;
  #pragma unroll
  for (int i = ty; i < 32; i += 8) {
    const size_t gi = ((size_t)(b * Dm + d0 + i)) * Tt + t0 + tx;
    ts[i][tx] = src[gi];
    tp[i][tx] = pose[gi];
  }
  __syncthreads();
  #pragma unroll
  for (int i = ty; i < 32; i += 8) {
    const size_t idx = ((size_t)(b * Tt + t0 + i)) * Dm + d0 + tx;
    const float s = ts[tx][i], p = tp[tx][i];
    g_x[idx] = s;
    g_pos[idx] = p;
    g_xb[idx] = f2b(s);
    g_qkb[idx] = f2b(s + p);
  }
}

__global__ __launch_bounds__(256) void trans_out_k(float* out) {
  __shared__ float tile[32][33];
  const int tx = threadIdx.x & 31, ty = threadIdx.x >> 5;
  const int t0 = blockIdx.x * 32, d0 = blockIdx.y * 32, b = blockIdx.z;
  #pragma unroll
  for (int i = ty; i < 32; i += 8)
    tile[i][tx] = g_x[((size_t)(b * Tt + t0 + i)) * Dm + d0 + tx];
  __syncthreads();
  #pragma unroll
  for (int i = ty; i < 32; i += 8)
    out[((size_t)(b * Dm + d0 + i)) * Tt + t0 + tx] = tile[tx][i];
}

// ---------------------------------------------------------------------------
// MFMA GEMM for K=256 mid-size-grid cases (KQ, V, attn-out): BM=128, BN=64,
// BK=64; 4 waves (2x2). 3 LDS buffers, ONE barrier per K-step, stage
// hoisted before compute (round-4 structure). LDS 72KB -> 2 blocks/CU.
// DUAL (N=512 merged KQ): n0<256 -> Cid, n0>=256 -> C2id, stride 256.
// PERB: per-batch weights g_wo2 (13 m-blocks x NB per b), guarded stores.
template<int BN, bool DUAL, bool PERB, bool RELU, bool BIAS, bool CBF16>
__global__ __launch_bounds__(256) void gemm2_k(
    int Aid, int woff, const float* __restrict__ bias, int Cid, int C2id,
    int NB, int M, int N, int K) {
  constexpr int BM = 128, BK = 64;
  constexpr int ACH = BM * 8;           // 1024 short8 (16 KB)
  constexpr int BCH = BN * 8;           // 512 short8 (8 KB)
  constexpr int NW = BN / 32;           // n-frags per wave
  __shared__ short8 As8[3][ACH];
  __shared__ short8 Bs8[3][BCH];
  const int tid = threadIdx.x;
  const int lane = tid & 63, wid = tid >> 6;
  const int wr = wid >> 1, wc = wid & 1;

  // XCD-aware bijective remap (m204).
  const int nwg = gridDim.x;
  const int bid = blockIdx.x;
  const int q = nwg >> 3, r = nwg & 7;
  const int xcd = bid & 7, seq = bid >> 3;
  const int wgid = (xcd < r ? xcd * (q + 1) : r * (q + 1) + (xcd - r) * q) + seq;

  int m0, n0, mlim;
  const unsigned short* W16;
  if constexpr (PERB) {
    const int per = 13 * NB;
    const int b = wgid / per;
    const int rem = wgid - b * per;
    m0 = b * Tt + (rem / NB) * BM;
    n0 = (rem % NB) * BN;
    mlim = b * Tt + Tt;
    W16 = g_wo2 + (size_t)b * 65536;
  } else {
    m0 = (wgid / NB) * BM;
    n0 = (wgid % NB) * BN;
    mlim = M;
    W16 = g_wb + woff;
  }

  const unsigned short* A16 = selbufb(Aid);
  const bool second = DUAL && (n0 >= 256);
  float* Cf = selbuf(second ? C2id : Cid);
  unsigned short* C16 = selbufb(second ? C2id : Cid);
  const int gn0 = second ? n0 - 256 : n0;
  const int cstride = DUAL ? 256 : N;

  f32x4 acc[4][NW];
  #pragma unroll
  for (int m = 0; m < 4; ++m)
    #pragma unroll
    for (int n = 0; n < NW; ++n) acc[m][n] = (f32x4){0.f, 0.f, 0.f, 0.f};

  const int lkc = lane >> 4, lrc = lane & 15;

  auto stage = [&](int t, int buf) {
    const int k0 = t * BK;
    #pragma unroll
    for (int i = 0; i < ACH / 256; ++i) {
      const int c = tid + i * 256;
      const int row = c >> 3, kc = c & 7;
      const unsigned short* gs = A16 + (size_t)(m0 + row) * K + k0 +
                                 ((kc ^ (row & 7)) << 3);
      __builtin_amdgcn_global_load_lds(
          (const __attribute__((address_space(1))) u32*)gs,
          (__attribute__((address_space(3))) u32*)&As8[buf][c], 16, 0, 0);
    }
    #pragma unroll
    for (int i = 0; i < BCH / 256; ++i) {
      const int c = tid + i * 256;
      const int row = c >> 3, kc = c & 7;
      const unsigned short* gs = W16 + (size_t)(n0 + row) * K + k0 +
                                 ((kc ^ (row & 7)) << 3);
      __builtin_amdgcn_global_load_lds(
          (const __attribute__((address_space(1))) u32*)gs,
          (__attribute__((address_space(3))) u32*)&Bs8[buf][c], 16, 0, 0);
    }
  };

  const int nt = K / BK;
  stage(0, 0);
  if (nt > 1) stage(1, 1);
  int cur = 0, nxt = 2;                 // nxt = (t+2)%3 target
  for (int t = 0; t < nt; ++t) {
    if (t + 1 < nt) {
      asm volatile("s_waitcnt vmcnt(6)" ::: "memory");
    } else {
      asm volatile("s_waitcnt vmcnt(0)" ::: "memory");
    }
    __builtin_amdgcn_sched_barrier(0);
    __builtin_amdgcn_s_barrier();       // buf[cur] landed for ALL waves;
                                        // ALL waves done reading buf[nxt]
    __builtin_amdgcn_sched_barrier(0);
    if (t + 2 < nt) stage(t + 2, nxt);  // overlaps with compute below
    #pragma unroll
    for (int kk = 0; kk < 2; ++kk) {
      short8 af[4], bf[NW];
      #pragma unroll
      for (int m = 0; m < 4; ++m) {
        const int r2 = wr * 64 + m * 16 + lrc;
        af[m] = As8[cur][r2 * 8 + ((kk * 4 + lkc) ^ (r2 & 7))];
      }
      #pragma unroll
      for (int n = 0; n < NW; ++n) {
        const int cn = wc * (BN / 2) + n * 16 + lrc;
        bf[n] = Bs8[cur][cn * 8 + ((kk * 4 + lkc) ^ (cn & 7))];
      }
      #pragma unroll
      for (int m = 0; m < 4; ++m)
        #pragma unroll
        for (int n = 0; n < NW; ++n)
          acc[m][n] = __builtin_amdgcn_mfma_f32_16x16x32_bf16(
              af[m], bf[n], acc[m][n], 0, 0, 0);
    }
    cur = (cur == 2) ? 0 : cur + 1;
    nxt = (nxt == 2) ? 0 : nxt + 1;
  }

  // ---- LDS-staged epilogue: deposit acc, then coalesced row stores ----
  constexpr int CSTR = (BN == 64) ? BN + 4 : BN;
  float* ldsC = (float*)&As8[0][0];
  {
    asm volatile("s_waitcnt vmcnt(0)" ::: "memory");
    __builtin_amdgcn_s_barrier();       // all waves done reading As8/Bs8
    const int r0 = lkc * 4;
    #pragma unroll
    for (int m = 0; m < 4; ++m)
      #pragma unroll
      for (int n = 0; n < NW; ++n) {
        const int col = wc * (BN / 2) + n * 16 + lrc;
        #pragma unroll
        for (int j = 0; j < 4; ++j)
          ldsC[(wr * 64 + m * 16 + r0 + j) * CSTR + col] = acc[m][n][j];
      }
    __syncthreads();
  }
  if constexpr (CBF16) {
    constexpr int CH = BM * BN / 8;     // short8 chunks
    #pragma unroll
    for (int i = 0; i < CH / 256; ++i) {
      const int c = tid + i * 256;
      const int rowl = c / (BN / 8), col8 = (c % (BN / 8)) * 8;
      if (PERB && m0 + rowl >= mlim) continue;
      short8 v;
      #pragma unroll
      for (int j = 0; j < 8; ++j) {
        float x = ldsC[rowl * CSTR + col8 + j];
        if (BIAS) x += bias[gn0 + col8 + j];
        if (RELU) x = fmaxf(x, 0.f);
        v[j] = (short)f2b(x);
      }
      *(short8*)(C16 + (size_t)(m0 + rowl) * cstride + gn0 + col8) = v;
    }
  } else {
    constexpr int CH = BM * BN / 4;     // float4 chunks
    #pragma unroll
    for (int i = 0; i < CH / 256; ++i) {
      const int c = tid + i * 256;
      const int rowl = c / (BN / 4), col4 = (c % (BN / 4)) * 4;
      if (PERB && m0 + rowl >= mlim) continue;
      float4 v;
      float* pv = &v.x;
      #pragma unroll
      for (int j = 0; j < 4; ++j) {
        float x = ldsC[rowl * CSTR + col4 + j];
        if (BIAS) x += bias[gn0 + col4 + j];
        if (RELU) x = fmaxf(x, 0.f);
        pv[j] = x;
      }
      *(float4*)(Cf + (size_t)(m0 + rowl) * cstride + gn0 + col4) = v;
    }
  }
}

// ---------------------------------------------------------------------------
// FUSED FF v2 (round-8): out_q = relu(A @ W1q^T + b1) @ W2q^T for one
// 512-wide QUARTER of the hidden dim. Grid 500 = 125 m-blocks x 4 quarters;
// q0 -> g_qk (+b2), q1 -> g_t, q2/q3 -> f32 views of g_ffh; ln2 sums all 4.
// v1 lessons (77.7us, LDS-read bound): (1) A-fragments HOISTED TO REGISTERS
// (each wave's GEMM1 rows fixed across chunks) -> kills 64KB/chunk LDS reads
// and frees the A buffer: W dbuf overlays it (union ws) -> LDS 74KB,
// 2 blocks/CU. (2) GEMM1 wave tile 32x16 (4Mx2N): w1 broadcast mult 8->4.
// (3) quarter-split: W-broadcast volume invariant, but 2 blocks/CU TLP and
// half the serial chain. 2 barriers/chunk (single h buffer: h(ch) reads
// complete before barrier-A(ch+1)). launch_bounds(512,4) caps VGPR at 128
// (areg 32 + acc2 64 + frags) for the 4 waves/SIMD needed by 2 blocks/CU.
__global__ __launch_bounds__(512, 4) void gemmf_k(
    int Aid, int w1off, int w2off, const float* __restrict__ b1p,
    const float* __restrict__ b2p) {
  constexpr int BM = 128, NCH = 16;     // 16 chunks x 32 hidden = 512
  __shared__ short8 ws[4096];           // 64 KB: A (prologue) then W dbuf:
                                        // [buf*2048 + w1c:1024 | w2c:1024]
  __shared__ short8 h8[512];            // 8 KB: h 128x32 bf16 (swizzled)
  __shared__ float b1f[512];            // 2 KB
  const int tid = threadIdx.x;
  const int lane = tid & 63, wid = tid >> 6;     // 8 waves
  const int lkc = lane >> 4, lrc = lane & 15;
  const int nwg = gridDim.x, bid = blockIdx.x;
  const int q = nwg >> 3, r = nwg & 7;
  const int xcd = bid & 7, seq = bid >> 3;
  const int wgid = (xcd < r ? xcd * (q + 1) : r * (q + 1) + (xcd - r) * q) + seq;
  const int qd = wgid / 125;            // hidden quarter 0..3
  const int m0 = (wgid - qd * 125) * BM;
  const int hb = qd * 512;              // hidden base
  const unsigned short* A16 = selbufb(Aid);
  const unsigned short* W1p = g_wb + w1off;
  const unsigned short* W2p = g_wb + w2off;
  float* Cf;
  if (qd == 0) Cf = g_qk;
  else if (qd == 1) Cf = g_t;
  else Cf = (float*)g_ffh + (size_t)(qd - 2) * Fsz;

  // ---- prologue: stage A (8/thr) + b1 (1/thr) into LDS ----
  #pragma unroll
  for (int i = 0; i < 8; ++i) {
    const int c = tid + i * 512;
    const int row = c >> 5, kc = c & 31;
    const unsigned short* gs = A16 + (size_t)(m0 + row) * 256 +
                               ((kc ^ (row & 31)) << 3);
    __builtin_amdgcn_global_load_lds(
        (const __attribute__((address_space(1))) u32*)gs,
        (__attribute__((address_space(3))) u32*)&ws[c], 16, 0, 0);
  }
  __builtin_amdgcn_global_load_lds(
      (const __attribute__((address_space(1))) u32*)(b1p + hb + tid),
      (__attribute__((address_space(3))) u32*)&b1f[tid], 4, 0, 0);
  asm volatile("s_waitcnt vmcnt(0)" ::: "memory");
  __builtin_amdgcn_sched_barrier(0);
  __builtin_amdgcn_s_barrier();

  // ---- hoist this wave's A fragments (32 rows) into registers ----
  const int mg = wid >> 1, ng = wid & 1;         // GEMM1: 4M(32r) x 2N(16c)
  short8 areg[2][8];
  #pragma unroll
  for (int m = 0; m < 2; ++m)
    #pragma unroll
    for (int s = 0; s < 8; ++s) {
      const int r2 = mg * 32 + m * 16 + lrc;
      areg[m][s] = ws[r2 * 32 + ((s * 4 + lkc) ^ (r2 & 31))];
    }
  asm volatile("s_waitcnt lgkmcnt(0)" ::: "memory");
  __builtin_amdgcn_sched_barrier(0);
  __builtin_amdgcn_s_barrier();         // all waves done reading A from ws

  auto stage_w = [&](int ch, int buf) {
    const int kb = hb + ch * 32;
    #pragma unroll
    for (int i = 0; i < 2; ++i) {       // W1c: 32 rows x 256 k
      const int c = tid + i * 512;
      const int row = c >> 5, kc = c & 31;
      const unsigned short* gs = W1p + (size_t)(kb + row) * 256 +
                                 ((kc ^ (row & 31)) << 3);
      __builtin_amdgcn_global_load_lds(
          (const __attribute__((address_space(1))) u32*)gs,
          (__attribute__((address_space(3))) u32*)&ws[buf * 2048 + c], 16, 0, 0);
    }
    #pragma unroll
    for (int i = 0; i < 2; ++i) {       // W2c: 256 rows x 32 k (stride 2048)
      const int c = tid + i * 512;
      const int row = c >> 2, kc = c & 3;
      const int g = (kc ^ (row & 3) ^ ((row >> 2) & 3)) & 3;
      const unsigned short* gs = W2p + (size_t)row * 2048 + kb + (g << 3);
      __builtin_amdgcn_global_load_lds(
          (const __attribute__((address_space(1))) u32*)gs,
          (__attribute__((address_space(3))) u32*)&ws[buf * 2048 + 1024 + c],
          16, 0, 0);
    }
  };
  stage_w(0, 0);

  const int wr = wid >> 2, wc = wid & 3;         // GEMM2: 2x4 waves, 64x64
  f32x4 acc2[4][4];
  #pragma unroll
  for (int m = 0; m < 4; ++m)
    #pragma unroll
    for (int n = 0; n < 4; ++n) acc2[m][n] = (f32x4){0.f, 0.f, 0.f, 0.f};

  for (int ch = 0; ch < NCH; ++ch) {
    const int cur = ch & 1;
    const int wb = cur * 2048;
    asm volatile("s_waitcnt vmcnt(0)" ::: "memory");   // W(ch) landed (mine)
    __builtin_amdgcn_sched_barrier(0);
    __builtin_amdgcn_s_barrier();       // barrier A: W(ch) landed for ALL;
                                        // GEMM1/2(ch-1) reads of buf^1 done
    __builtin_amdgcn_sched_barrier(0);
    if (ch + 1 < NCH) stage_w(ch + 1, cur ^ 1);

    // ---- GEMM1: h = relu(A @ W1c^T + b1); A from regs, 8 bf reads ----
    f32x4 a1[2];
    a1[0] = (f32x4){0.f, 0.f, 0.f, 0.f};
    a1[1] = (f32x4){0.f, 0.f, 0.f, 0.f};
    const int cn1 = ng * 16 + lrc;
    #pragma unroll
    for (int s = 0; s < 8; ++s) {
      short8 bf = ws[wb + cn1 * 32 + ((s * 4 + lkc) ^ cn1)];
      a1[0] = __builtin_amdgcn_mfma_f32_16x16x32_bf16(areg[0][s], bf, a1[0], 0, 0, 0);
      a1[1] = __builtin_amdgcn_mfma_f32_16x16x32_bf16(areg[1][s], bf, a1[1], 0, 0, 0);
    }
    // bias + relu + bf16 -> h LDS (swizzled for GEMM2 reads)
    unsigned short* h16 = (unsigned short*)h8;
    #pragma unroll
    for (int m = 0; m < 2; ++m)
      #pragma unroll
      for (int j = 0; j < 4; ++j) {
        const int row = mg * 32 + m * 16 + lkc * 4 + j;
        const float v = fmaxf(a1[m][j] + b1f[ch * 32 + cn1], 0.f);
        const int g = ((cn1 >> 3) ^ (row & 3) ^ ((row >> 2) & 3)) & 3;
        h16[row * 32 + g * 8 + (cn1 & 7)] = f2b(v);
      }
    asm volatile("s_waitcnt lgkmcnt(0)" ::: "memory");
    __builtin_amdgcn_sched_barrier(0);
    __builtin_amdgcn_s_barrier();       // barrier B: h visible to all waves
    __builtin_amdgcn_sched_barrier(0);

    // ---- GEMM2: acc2 += h @ W2c^T (K=32) ----
    short8 af2[4], bf2[4];
    #pragma unroll
    for (int m = 0; m < 4; ++m) {
      const int r2 = wr * 64 + m * 16 + lrc;
      af2[m] = h8[r2 * 4 + ((lkc ^ (r2 & 3) ^ ((r2 >> 2) & 3)) & 3)];
    }
    #pragma unroll
    for (int n = 0; n < 4; ++n) {
      const int cn = wc * 64 + n * 16 + lrc;
      bf2[n] = ws[wb + 1024 + cn * 4 + ((lkc ^ (cn & 3) ^ ((cn >> 2) & 3)) & 3)];
    }
    #pragma unroll
    for (int m = 0; m < 4; ++m)
      #pragma unroll
      for (int n = 0; n < 4; ++n)
        acc2[m][n] = __builtin_amdgcn_mfma_f32_16x16x32_bf16(
            af2[m], bf2[n], acc2[m][n], 0, 0, 0);
  }

  // ---- direct fp32 epilogue (quarter 0 adds b2) ----
  const int r0 = lkc * 4;
  #pragma unroll
  for (int m = 0; m < 4; ++m) {
    const int gm = m0 + wr * 64 + m * 16 + r0;
    #pragma unroll
    for (int n = 0; n < 4; ++n) {
      const int gn = wc * 64 + n * 16 + lrc;
      const float bb = (qd == 0) ? b2p[gn] : 0.f;
      #pragma unroll
      for (int j = 0; j < 4; ++j)
        Cf[(size_t)(gm + j) * 256 + gn] = acc2[m][n][j] + bb;
    }
  }
}

// ---------------------------------------------------------------------------
// Conv compression, K and V in one dispatch (blockIdx.z): z=0 reads g_tb
// (k proj) -> g_kc with null_k edge; z=1 reads g_ffh (v proj) -> g_vc.
__global__ __launch_bounds__(256) void compress2_k(
    const float* __restrict__ cw, const float* __restrict__ cb,
    const float* __restrict__ nk, const float* __restrict__ nv) {
  __shared__ float rows[32][256];       // 32 KB
  const int tc0 = 1 + blockIdx.x * 16;
  const int b = blockIdx.y;
  const int z = blockIdx.z;
  const int tid = threadIdx.x;
  const int o = tid;
  const int g = o >> 5;

  const unsigned short* srcbuf = z ? g_ffh : g_tb;
  const float* nul = z ? nv : nk;
  float* outb = (z ? g_vc : g_kc) + (size_t)b * Tkv * Dm;

  const int r0g = 2 * tc0 - 2;
  const unsigned short* src = srcbuf + ((size_t)b * Tt + r0g) * Dm;
  #pragma unroll
  for (int i = 0; i < 4; ++i) {
    const int c = tid + i * 256;        // 1024 chunks of 8
    const int row = c >> 5, off = (c & 31) * 8;
    short8 v = *(const short8*)(src + (size_t)row * 256 + off);
    #pragma unroll
    for (int j = 0; j < 8; ++j)
      rows[row][off + j] = b2f((unsigned short)v[j]);
  }

  float we[32], wo[32];
  {
    const float4* wp = (const float4*)(cw + o * 64);
    #pragma unroll
    for (int i = 0; i < 16; ++i) {
      float4 w4 = wp[i];
      we[i * 2 + 0] = w4.x; wo[i * 2 + 0] = w4.y;
      we[i * 2 + 1] = w4.z; wo[i * 2 + 1] = w4.w;
    }
  }
  const float bias = cb[o];
  if (blockIdx.x == 0) {                // edge rows j=0,1
    outb[o] = nul[b * Dm + o];
    outb[Dm + o] = bias;
  }
  __syncthreads();

  float* outp = outb + o;
  #pragma unroll
  for (int t = 0; t < 16; ++t) {
    const int lr = 2 * t;
    const float* p0 = &rows[lr][g * 32];
    const float* p1 = &rows[lr + 1][g * 32];
    float acc = bias;
    #pragma unroll
    for (int i4 = 0; i4 < 8; ++i4) {
      float4 a0 = *(const float4*)(p0 + i4 * 4);
      float4 a1 = *(const float4*)(p1 + i4 * 4);
      acc = fmaf(we[i4 * 4 + 0], a0.x, acc);
      acc = fmaf(we[i4 * 4 + 1], a0.y, acc);
      acc = fmaf(we[i4 * 4 + 2], a0.z, acc);
      acc = fmaf(we[i4 * 4 + 3], a0.w, acc);
      acc = fmaf(wo[i4 * 4 + 0], a1.x, acc);
      acc = fmaf(wo[i4 * 4 + 1], a1.y, acc);
      acc = fmaf(wo[i4 * 4 + 2], a1.z, acc);
      acc = fmaf(wo[i4 * 4 + 3], a1.w, acc);
    }
    outp[(size_t)(1 + tc0 + t) * Dm] = acc;
  }
}

// ---------------------------------------------------------------------------
// KV reduction stage 1/2 (validated).
__global__ __launch_bounds__(256) void kvout1_k() {
  __shared__ float kl[8][32];
  __shared__ float vl[8][32];
  const int bh = blockIdx.x;
  const int js = blockIdx.y;
  const int b = bh >> 3, h = bh & 7;
  const int j0 = js * 101;
  const int jend = (j0 + 101 < Tkv) ? j0 + 101 : Tkv;

  const int tid = threadIdx.x;
  const int lr = tid >> 5;
  const int lc = tid & 31;
  const int e = tid >> 3;
  const int d0 = (tid & 7) * 4;

  float a0 = 0.f, a1 = 0.f, a2 = 0.f, a3 = 0.f;
  const size_t base = (size_t)b * Tkv * Dm + h * 32;

  for (int jc = j0; jc < jend; jc += 8) {
    const int jr = jc + lr;
    if (jr < jend) {
      kl[lr][lc] = g_kc[base + (size_t)jr * Dm + lc];
      vl[lr][lc] = g_vc[base + (size_t)jr * Dm + lc];
    } else {
      kl[lr][lc] = 0.f;
      vl[lr][lc] = 0.f;
    }
    __syncthreads();
    #pragma unroll
    for (int r = 0; r < 8; ++r) {
      const float kf = kl[r][e];
      const float* vr = &vl[r][d0];
      a0 = fmaf(kf, vr[0], a0);
      a1 = fmaf(kf, vr[1], a1);
      a2 = fmaf(kf, vr[2], a2);
      a3 = fmaf(kf, vr[3], a3);
    }
    __syncthreads();
  }
  float* op = g_kvp + ((size_t)js * 80 + bh) * 1024 + e * 32 + d0;
  op[0] = a0; op[1] = a1; op[2] = a2; op[3] = a3;
}

__global__ __launch_bounds__(256) void kvout2_k() {
  const int bh = blockIdx.x;
  const int tid = threadIdx.x;
  const int e = tid >> 3;
  const int d0 = (tid & 7) * 4;
  float a0 = 0.f, a1 = 0.f, a2 = 0.f, a3 = 0.f;
  #pragma unroll
  for (int s = 0; s < JCH; ++s) {
    const float* p = g_kvp + ((size_t)s * 80 + bh) * 1024 + e * 32 + d0;
    a0 += p[0]; a1 += p[1]; a2 += p[2]; a3 += p[3];
  }
  float* op = g_kvm + (size_t)bh * 1024 + e * 32 + d0;
  op[0] = a0 * 0.0625f;
  op[1] = a1 * 0.0625f;
  op[2] = a2 * 0.0625f;
  op[3] = a3 * 0.0625f;
}

// ---------------------------------------------------------------------------
// W'[b,n,h*32+e] = sum_d kvm[b,h,e,d] * Wo[n,h*32+d]   (bf16 out)
__global__ __launch_bounds__(256) void wo2_k(int wooff) {
  const int n = blockIdx.x, b = blockIdx.y;
  const int he = threadIdx.x;
  const int h = he >> 5, e = he & 31;
  const float* kp = g_kvm + ((size_t)(b * Hh + h) * 32 + e) * 32;
  const unsigned short* wp = g_wb + wooff + (size_t)n * Dm + h * 32;
  float acc = 0.f;
  #pragma unroll
  for (int d = 0; d < 32; ++d) acc = fmaf(kp[d], b2f(wp[d]), acc);
  g_wo2[(size_t)b * 65536 + (size_t)n * Dm + he] = f2b(acc);
}

// ---------------------------------------------------------------------------
// x = LN(x + d1 [+ d2 + d3 + d4])*g + beta (fp32), writes bf16 shadow g_xb.
// If do_pos: also writes g_qkb = bf16(ln_out + pos).
__global__ __launch_bounds__(256) void ln_k(int did, int did2, int did3,
                                            int did4, const float* g,
                                            const float* beta, int do_pos) {
  const int lane = threadIdx.x & 63;
  const int wave = threadIdx.x >> 6;
  const size_t row = (size_t)blockIdx.x * 4 + wave;
  float4 xv = ((const float4*)g_x)[row * 64 + lane];
  float4 dv = ((const float4*)selbuf(did))[row * 64 + lane];
  float v[4] = {xv.x + dv.x, xv.y + dv.y, xv.z + dv.z, xv.w + dv.w};
  if (did2 >= 0) {
    float4 d2 = ((const float4*)selbuf(did2))[row * 64 + lane];
    v[0] += d2.x; v[1] += d2.y; v[2] += d2.z; v[3] += d2.w;
  }
  if (did3 >= 0) {
    float4 d3 = ((const float4*)selbuf(did3))[row * 64 + lane];
    v[0] += d3.x; v[1] += d3.y; v[2] += d3.z; v[3] += d3.w;
  }
  if (did4 >= 0) {
    float4 d4 = ((const float4*)selbuf(did4))[row * 64 + lane];
    v[0] += d4.x; v[1] += d4.y; v[2] += d4.z; v[3] += d4.w;
  }
  float sum = v[0] + v[1] + v[2] + v[3];
  float sq = v[0]*v[0] + v[1]*v[1] + v[2]*v[2] + v[3]*v[3];
  #pragma unroll
  for (int off = 32; off; off >>= 1) {
    sum += __shfl_xor(sum, off);
    sq  += __shfl_xor(sq, off);
  }
  const float mean = sum * (1.f / 256.f);
  const float var = sq * (1.f / 256.f) - mean * mean;
  const float rs = rsqrtf(var + 1e-5f);
  float4 gg = ((const float4*)g)[lane];
  float4 bb = ((const float4*)beta)[lane];
  float4 ov;
  ov.x = (v[0] - mean) * rs * gg.x + bb.x;
  ov.y = (v[1] - mean) * rs * gg.y + bb.y;
  ov.z = (v[2] - mean) * rs * gg.z + bb.z;
  ov.w = (v[3] - mean) * rs * gg.w + bb.w;
  ((float4*)g_x)[row * 64 + lane] = ov;
  short4v sv;
  sv[0] = (short)f2b(ov.x); sv[1] = (short)f2b(ov.y);
  sv[2] = (short)f2b(ov.z); sv[3] = (short)f2b(ov.w);
  *(short4v*)&g_xb[(row * 64 + lane) * 4] = sv;
  if (do_pos) {
    float4 pv = ((const float4*)g_pos)[row * 64 + lane];
    short4v qv;
    qv[0] = (short)f2b(ov.x + pv.x); qv[1] = (short)f2b(ov.y + pv.y);
    qv[2] = (short)f2b(ov.z + pv.z); qv[3] = (short)f2b(ov.w + pv.w);
    *(short4v*)&g_qkb[(row * 64 + lane) * 4] = qv;
  }
}

// ---------------------------------------------------------------------------
extern "C" void kernel_launch(void* const* d_in, const int* in_sizes, int n_in,
                              void* d_out, int out_size, void* d_ws, size_t ws_size,
                              hipStream_t stream) {
  const float* src  = (const float*)d_in[0];
  const float* pose = (const float*)d_in[1];
  const float* Wq   = (const float*)d_in[2];
  const float* Wk   = (const float*)d_in[3];
  const float* Wv   = (const float*)d_in[4];
  const float* Wo   = (const float*)d_in[5];
  const float* bo   = (const float*)d_in[6];
  const float* cw   = (const float*)d_in[7];
  const float* cb   = (const float*)d_in[8];
  const float* nk   = (const float*)d_in[9];
  const float* nv   = (const float*)d_in[10];
  const float* ln1g = (const float*)d_in[11];
  const float* ln1b = (const float*)d_in[12];
  const float* ln2g = (const float*)d_in[13];
  const float* ln2b = (const float*)d_in[14];
  const float* W1   = (const float*)d_in[15];
  const float* b1   = (const float*)d_in[16];
  const float* W2   = (const float*)d_in[17];
  const float* b2   = (const float*)d_in[18];

  const int MT = Bsz * Tt;        // 16000
  const dim3 tgrid(Tt / 32, Dm / 32, Bsz);

  // g_wb layout: per-layer [Wk|Wq] at l*131072; then Wv, Wo, W1, W2.
  const int OV = 262144, OO = 393216, O1 = 524288, O2 = 1572864;
  wconv_all_k<<<10240, 256, 0, stream>>>(Wk, Wq, Wv, Wo, W1, W2);
  trans_in2_k<<<tgrid, 256, 0, stream>>>(src, pose);  // x, xb, pos, qkb

  const int MB = MT / 128;  // 125 m-blocks
  for (int l = 0; l < 2; ++l) {
    const float* bo_l = bo + (size_t)l * Dm;
    const float* cw_l = cw + (size_t)l * Dm * 64;
    const float* cb_l = cb + (size_t)l * Dm;
    const float* nk_l = nk + (size_t)l * Bsz * Dm;
    const float* nv_l = nv + (size_t)l * Bsz * Dm;
    const float* b1_l = b1 + (size_t)l * FFd;
    const float* b2_l = b2 + (size_t)l * Dm;
    const int wkq = l * 131072;
    const int wv = OV + l * 65536, wo = OO + l * 65536;
    const int w1 = O1 + l * 524288, w2 = O2 + l * 524288;

    // [k|q] = qkb @ [Wk|Wq]^T : k -> tb, q -> qb (DUAL, NB=8, grid 1000)
    gemm2_k<64, true, false, false, false, true><<<8 * MB, 256, 0, stream>>>(
        1, wkq, nullptr, 2, 4, 8, MT, 512, Dm);
    // v = xb @ Wv^T -> ffh (scratch)  (NB=4, grid 500)
    gemm2_k<64, false, false, false, false, true><<<4 * MB, 256, 0, stream>>>(
        0, wv, nullptr, 3, 3, 4, MT, Dm, Dm);
    // compress K (tb->kc) and V (ffh->vc) in one dispatch
    compress2_k<<<dim3(50, Bsz, 2), 256, 0, stream>>>(cw_l, cb_l, nk_l, nv_l);
    // kvm = (1/16) kc^T vc
    kvout1_k<<<dim3(Bsz * Hh, JCH), 256, 0, stream>>>();
    kvout2_k<<<Bsz * Hh, 256, 0, stream>>>();
    // W' = kvm (×) Wo  (per-b fused attn+Wo weights)
    wo2_k<<<dim3(Dm, Bsz), 256, 0, stream>>>(wo);
    // t = qb @ W'^T + bo (fp32, per-b, PERB; grid 520)
    gemm2_k<64, false, true, false, true, false><<<Bsz * 13 * 4, 256, 0, stream>>>(
        4, 0, bo_l, 2, 2, 4, MT, Dm, Dm);
    ln_k<<<MT / 4, 256, 0, stream>>>(2, -1, -1, -1,
                                     ln1g + l * Dm, ln1b + l * Dm, 0);

    // Fused FF v2: 4 hidden quarters -> g_qk(+b2), g_t, ffh0, ffh1 [grid 500]
    gemmf_k<<<500, 512, 0, stream>>>(0, w1, w2, b1_l, b2_l);
    // LN2 sums all 4 FF quarters; layer 0 fused with next layer's pos-add.
    ln_k<<<MT / 4, 256, 0, stream>>>(1, 2, 6, 7,
                                     ln2g + l * Dm, ln2b + l * Dm,
                                     l == 0 ? 1 : 0);
  }

  trans_out_k<<<tgrid, 256, 0, stream>>>((float*)d_out);
}

// Round 9
// 372.687 us; speedup vs baseline: 1.3734x; 1.3734x over previous
//
#include <hip/hip_runtime.h>
#include <math.h>

typedef __attribute__((ext_vector_type(8))) short short8;   // 8 bf16
typedef __attribute__((ext_vector_type(4))) short short4v;  // 4 bf16
typedef __attribute__((ext_vector_type(4))) float f32x4;
typedef unsigned int u32;

constexpr int Bsz = 10;
constexpr int Dm  = 256;
constexpr int Hh  = 8;
constexpr int Tt  = 1600;
constexpr int FFd = 2048;
constexpr int Tkv = 802;   // 1 null + 801 compressed
constexpr int JCH = 8;     // j-splits for kv reduction
constexpr size_t Fsz  = (size_t)Bsz * Tt * Dm;    // 4,096,000
constexpr size_t PAD  = 65536;
constexpr size_t KVsz = (size_t)Bsz * Tkv * Dm;   // 2,053,120
constexpr size_t FHsz = (size_t)Bsz * Tt * FFd;   // 32,768,000
constexpr size_t WBsz = 2621440;                  // all weights, bf16

// Static device scratch; referenced ONLY from device code.
__device__ float g_x[Fsz];                        // residual stream fp32
__device__ float g_qk[Fsz];                       // FF half0 out (LN2 d1)
__device__ float g_t[Fsz];                        // Wo out / FF half1 (LN2 d2)
__device__ float g_kc[KVsz];                      // compressed K
__device__ float g_vc[KVsz];                      // compressed V
__device__ float g_kvm[(size_t)Bsz * Hh * 32 * 32];
__device__ float g_kvp[(size_t)JCH * Bsz * Hh * 32 * 32];
__device__ float g_pos[Fsz];                      // transposed pos fp32
__device__ unsigned short g_xb[Fsz + PAD];        // bf16 shadow of x
__device__ unsigned short g_qkb[Fsz + PAD];       // bf16 x+pos
__device__ unsigned short g_tb[Fsz + PAD];        // bf16 k projection
__device__ unsigned short g_qb[Fsz + PAD];        // bf16 q projection
__device__ __attribute__((aligned(16))) unsigned short g_ffh[FHsz + PAD]; // v proj
__device__ unsigned short g_wb[WBsz];             // bf16 weights
__device__ unsigned short g_wo2[(size_t)Bsz * Dm * Dm];  // per-b fused kvm*Wo

__device__ __forceinline__ float* selbuf(int id) {
  switch (id) {
    case 0: return g_x;
    case 1: return g_qk;
    case 2: return g_t;
    case 3: return g_kc;
    case 4: return g_vc;
    default: return g_kvm;
  }
}
__device__ __forceinline__ unsigned short* selbufb(int id) {
  switch (id) {
    case 0: return g_xb;
    case 1: return g_qkb;
    case 2: return g_tb;
    case 3: return g_ffh;
    default: return g_qb;
  }
}

// fp32 -> bf16 (RNE)
__device__ __forceinline__ unsigned short f2b(float x) {
  unsigned int u = __float_as_uint(x);
  u += 0x7FFFu + ((u >> 16) & 1u);
  return (unsigned short)(u >> 16);
}
__device__ __forceinline__ float b2f(unsigned short u) {
  return __uint_as_float(((unsigned int)u) << 16);
}

// ---------------------------------------------------------------------------
// ALL weight conversions in one dispatch. g_wb layout:
// [l0:Wk|Wq][l1:Wk|Wq] | Wv(l0,l1) | Wo(l0,l1) | W1(l0,l1) | W2(l0,l1)
__global__ __launch_bounds__(256) void wconv_all_k(
    const float* __restrict__ Wk, const float* __restrict__ Wq,
    const float* __restrict__ Wv, const float* __restrict__ Wo,
    const float* __restrict__ W1, const float* __restrict__ W2) {
  const int i = blockIdx.x * 256 + threadIdx.x;   // < 2,621,440
  float v;
  if (i < 262144) {
    const int l = i >> 17, r = i & 131071;
    v = (r < 65536) ? Wk[l * 65536 + r] : Wq[l * 65536 + (r - 65536)];
  } else if (i < 393216) {
    v = Wv[i - 262144];
  } else if (i < 524288) {
    v = Wo[i - 393216];
  } else if (i < 1572864) {
    v = W1[i - 524288];
  } else {
    v = W2[i - 1572864];
  }
  g_wb[i] = f2b(v);
}

// ---------------------------------------------------------------------------
// Fused input transpose + pos-add: src,pose [B,D,T] -> g_x, g_xb, g_pos,
// g_qkb = bf16(x+pos).
__global__ __launch_bounds__(256) void trans_in2_k(const float* __restrict__ src,
                                                   const float* __restrict__ pose) {
  __shared__ float ts[32][33];
  __shared__ float tp[32][33];
  const int tx = threadIdx.x & 31, ty = threadIdx.x >> 5;
  const int t0 = blockIdx.x * 32, d0 = blockIdx.y * 32, b = blockIdx.z;
  #pragma unroll
  for (int i = ty; i < 32; i += 8) {
    const size_t gi = ((size_t)(b * Dm + d0 + i)) * Tt + t0 + tx;
    ts[i][tx] = src[gi];
    tp[i][tx] = pose[gi];
  }
  __syncthreads();
  #pragma unroll
  for (int i = ty; i < 32; i += 8) {
    const size_t idx = ((size_t)(b * Tt + t0 + i)) * Dm + d0 + tx;
    const float s = ts[tx][i], p = tp[tx][i];
    g_x[idx] = s;
    g_pos[idx] = p;
    g_xb[idx] = f2b(s);
    g_qkb[idx] = f2b(s + p);
  }
}

__global__ __launch_bounds__(256) void trans_out_k(float* out) {
  __shared__ float tile[32][33];
  const int tx = threadIdx.x & 31, ty = threadIdx.x >> 5;
  const int t0 = blockIdx.x * 32, d0 = blockIdx.y * 32, b = blockIdx.z;
  #pragma unroll
  for (int i = ty; i < 32; i += 8)
    tile[i][tx] = g_x[((size_t)(b * Tt + t0 + i)) * Dm + d0 + tx];
  __syncthreads();
  #pragma unroll
  for (int i = ty; i < 32; i += 8)
    out[((size_t)(b * Dm + d0 + i)) * Tt + t0 + tx] = tile[tx][i];
}

// ---------------------------------------------------------------------------
// MFMA GEMM for K=256 mid-size-grid cases (KQ, V, attn-out): BM=128, BN=64,
// BK=64; 4 waves (2x2). 3 LDS buffers, ONE barrier per K-step, stage
// hoisted before compute (round-4 structure). LDS 72KB -> 2 blocks/CU.
// DUAL (N=512 merged KQ): n0<256 -> Cid, n0>=256 -> C2id, stride 256.
// PERB: per-batch weights g_wo2 (13 m-blocks x NB per b), guarded stores.
template<int BN, bool DUAL, bool PERB, bool RELU, bool BIAS, bool CBF16>
__global__ __launch_bounds__(256) void gemm2_k(
    int Aid, int woff, const float* __restrict__ bias, int Cid, int C2id,
    int NB, int M, int N, int K) {
  constexpr int BM = 128, BK = 64;
  constexpr int ACH = BM * 8;           // 1024 short8 (16 KB)
  constexpr int BCH = BN * 8;           // 512 short8 (8 KB)
  constexpr int NW = BN / 32;           // n-frags per wave
  __shared__ short8 As8[3][ACH];
  __shared__ short8 Bs8[3][BCH];
  const int tid = threadIdx.x;
  const int lane = tid & 63, wid = tid >> 6;
  const int wr = wid >> 1, wc = wid & 1;

  // XCD-aware bijective remap (m204).
  const int nwg = gridDim.x;
  const int bid = blockIdx.x;
  const int q = nwg >> 3, r = nwg & 7;
  const int xcd = bid & 7, seq = bid >> 3;
  const int wgid = (xcd < r ? xcd * (q + 1) : r * (q + 1) + (xcd - r) * q) + seq;

  int m0, n0, mlim;
  const unsigned short* W16;
  if constexpr (PERB) {
    const int per = 13 * NB;
    const int b = wgid / per;
    const int rem = wgid - b * per;
    m0 = b * Tt + (rem / NB) * BM;
    n0 = (rem % NB) * BN;
    mlim = b * Tt + Tt;
    W16 = g_wo2 + (size_t)b * 65536;
  } else {
    m0 = (wgid / NB) * BM;
    n0 = (wgid % NB) * BN;
    mlim = M;
    W16 = g_wb + woff;
  }

  const unsigned short* A16 = selbufb(Aid);
  const bool second = DUAL && (n0 >= 256);
  float* Cf = selbuf(second ? C2id : Cid);
  unsigned short* C16 = selbufb(second ? C2id : Cid);
  const int gn0 = second ? n0 - 256 : n0;
  const int cstride = DUAL ? 256 : N;

  f32x4 acc[4][NW];
  #pragma unroll
  for (int m = 0; m < 4; ++m)
    #pragma unroll
    for (int n = 0; n < NW; ++n) acc[m][n] = (f32x4){0.f, 0.f, 0.f, 0.f};

  const int lkc = lane >> 4, lrc = lane & 15;

  auto stage = [&](int t, int buf) {
    const int k0 = t * BK;
    #pragma unroll
    for (int i = 0; i < ACH / 256; ++i) {
      const int c = tid + i * 256;
      const int row = c >> 3, kc = c & 7;
      const unsigned short* gs = A16 + (size_t)(m0 + row) * K + k0 +
                                 ((kc ^ (row & 7)) << 3);
      __builtin_amdgcn_global_load_lds(
          (const __attribute__((address_space(1))) u32*)gs,
          (__attribute__((address_space(3))) u32*)&As8[buf][c], 16, 0, 0);
    }
    #pragma unroll
    for (int i = 0; i < BCH / 256; ++i) {
      const int c = tid + i * 256;
      const int row = c >> 3, kc = c & 7;
      const unsigned short* gs = W16 + (size_t)(n0 + row) * K + k0 +
                                 ((kc ^ (row & 7)) << 3);
      __builtin_amdgcn_global_load_lds(
          (const __attribute__((address_space(1))) u32*)gs,
          (__attribute__((address_space(3))) u32*)&Bs8[buf][c], 16, 0, 0);
    }
  };

  const int nt = K / BK;
  stage(0, 0);
  if (nt > 1) stage(1, 1);
  int cur = 0, nxt = 2;                 // nxt = (t+2)%3 target
  for (int t = 0; t < nt; ++t) {
    if (t + 1 < nt) {
      asm volatile("s_waitcnt vmcnt(6)" ::: "memory");
    } else {
      asm volatile("s_waitcnt vmcnt(0)" ::: "memory");
    }
    __builtin_amdgcn_sched_barrier(0);
    __builtin_amdgcn_s_barrier();       // buf[cur] landed for ALL waves;
                                        // ALL waves done reading buf[nxt]
    __builtin_amdgcn_sched_barrier(0);
    if (t + 2 < nt) stage(t + 2, nxt);  // overlaps with compute below
    #pragma unroll
    for (int kk = 0; kk < 2; ++kk) {
      short8 af[4], bf[NW];
      #pragma unroll
      for (int m = 0; m < 4; ++m) {
        const int r2 = wr * 64 + m * 16 + lrc;
        af[m] = As8[cur][r2 * 8 + ((kk * 4 + lkc) ^ (r2 & 7))];
      }
      #pragma unroll
      for (int n = 0; n < NW; ++n) {
        const int cn = wc * (BN / 2) + n * 16 + lrc;
        bf[n] = Bs8[cur][cn * 8 + ((kk * 4 + lkc) ^ (cn & 7))];
      }
      #pragma unroll
      for (int m = 0; m < 4; ++m)
        #pragma unroll
        for (int n = 0; n < NW; ++n)
          acc[m][n] = __builtin_amdgcn_mfma_f32_16x16x32_bf16(
              af[m], bf[n], acc[m][n], 0, 0, 0);
    }
    cur = (cur == 2) ? 0 : cur + 1;
    nxt = (nxt == 2) ? 0 : nxt + 1;
  }

  // ---- LDS-staged epilogue: deposit acc, then coalesced row stores ----
  constexpr int CSTR = (BN == 64) ? BN + 4 : BN;
  float* ldsC = (float*)&As8[0][0];
  {
    asm volatile("s_waitcnt vmcnt(0)" ::: "memory");
    __builtin_amdgcn_s_barrier();       // all waves done reading As8/Bs8
    const int r0 = lkc * 4;
    #pragma unroll
    for (int m = 0; m < 4; ++m)
      #pragma unroll
      for (int n = 0; n < NW; ++n) {
        const int col = wc * (BN / 2) + n * 16 + lrc;
        #pragma unroll
        for (int j = 0; j < 4; ++j)
          ldsC[(wr * 64 + m * 16 + r0 + j) * CSTR + col] = acc[m][n][j];
      }
    __syncthreads();
  }
  if constexpr (CBF16) {
    constexpr int CH = BM * BN / 8;     // short8 chunks
    #pragma unroll
    for (int i = 0; i < CH / 256; ++i) {
      const int c = tid + i * 256;
      const int rowl = c / (BN / 8), col8 = (c % (BN / 8)) * 8;
      if (PERB && m0 + rowl >= mlim) continue;
      short8 v;
      #pragma unroll
      for (int j = 0; j < 8; ++j) {
        float x = ldsC[rowl * CSTR + col8 + j];
        if (BIAS) x += bias[gn0 + col8 + j];
        if (RELU) x = fmaxf(x, 0.f);
        v[j] = (short)f2b(x);
      }
      *(short8*)(C16 + (size_t)(m0 + rowl) * cstride + gn0 + col8) = v;
    }
  } else {
    constexpr int CH = BM * BN / 4;     // float4 chunks
    #pragma unroll
    for (int i = 0; i < CH / 256; ++i) {
      const int c = tid + i * 256;
      const int rowl = c / (BN / 4), col4 = (c % (BN / 4)) * 4;
      if (PERB && m0 + rowl >= mlim) continue;
      float4 v;
      float* pv = &v.x;
      #pragma unroll
      for (int j = 0; j < 4; ++j) {
        float x = ldsC[rowl * CSTR + col4 + j];
        if (BIAS) x += bias[gn0 + col4 + j];
        if (RELU) x = fmaxf(x, 0.f);
        pv[j] = x;
      }
      *(float4*)(Cf + (size_t)(m0 + rowl) * cstride + gn0 + col4) = v;
    }
  }
}

// ---------------------------------------------------------------------------
// FUSED FF v3 (round-9): v2's LDS-traffic fixes on v1's known-good memory
// config. out_half = relu(A @ W1h^T + b1) @ W2h^T, half = 1024 hidden.
// Grid 250 = 125 m-blocks x 2 halves, 1 block/CU (launch_bounds(512,1):
// compiler free on registers -- v2's (512,4) forced a 64-VGPR cap and
// spilled acc2+areg to scratch: 400MB FETCH, 144us. r8 lesson).
// Kept from v2 (all on-device verified): A-frags hoisted to registers
// (-64KB/chunk LDS reads, W dbuf overlays freed A buffer); GEMM1 wave tile
// 32x16 (w1 broadcast 8->4, -64KB/chunk); 2 barriers/chunk.
// Per-chunk LDS traffic ~260KB (v1) -> ~140KB.
__global__ __launch_bounds__(512, 1) void gemmf_k(
    int Aid, int w1off, int w2off, const float* __restrict__ b1p,
    const float* __restrict__ b2p) {
  constexpr int BM = 128, NCH = 32;     // 32 chunks x 32 hidden = 1024
  __shared__ short8 ws[4096];           // 64 KB: A (prologue) then W dbuf:
                                        // [buf*2048 + w1c:1024 | w2c:1024]
  __shared__ short8 h8[512];            // 8 KB: h 128x32 bf16 (swizzled)
  __shared__ float b1f[1024];           // 4 KB
  const int tid = threadIdx.x;
  const int lane = tid & 63, wid = tid >> 6;     // 8 waves
  const int lkc = lane >> 4, lrc = lane & 15;
  const int nwg = gridDim.x, bid = blockIdx.x;
  const int q = nwg >> 3, r = nwg & 7;
  const int xcd = bid & 7, seq = bid >> 3;
  const int wgid = (xcd < r ? xcd * (q + 1) : r * (q + 1) + (xcd - r) * q) + seq;
  const int half = (wgid >= 125) ? 1 : 0;
  const int m0 = (wgid - half * 125) * BM;
  const int hb = half * 1024;           // hidden base
  const unsigned short* A16 = selbufb(Aid);
  const unsigned short* W1p = g_wb + w1off;
  const unsigned short* W2p = g_wb + w2off;
  float* Cf = half ? g_t : g_qk;

  // ---- prologue: stage A (8/thr) + b1 (2/thr) into LDS ----
  #pragma unroll
  for (int i = 0; i < 8; ++i) {
    const int c = tid + i * 512;
    const int row = c >> 5, kc = c & 31;
    const unsigned short* gs = A16 + (size_t)(m0 + row) * 256 +
                               ((kc ^ (row & 31)) << 3);
    __builtin_amdgcn_global_load_lds(
        (const __attribute__((address_space(1))) u32*)gs,
        (__attribute__((address_space(3))) u32*)&ws[c], 16, 0, 0);
  }
  #pragma unroll
  for (int i = 0; i < 2; ++i) {
    const int c = tid + i * 512;
    __builtin_amdgcn_global_load_lds(
        (const __attribute__((address_space(1))) u32*)(b1p + hb + c),
        (__attribute__((address_space(3))) u32*)&b1f[c], 4, 0, 0);
  }
  asm volatile("s_waitcnt vmcnt(0)" ::: "memory");
  __builtin_amdgcn_sched_barrier(0);
  __builtin_amdgcn_s_barrier();

  // ---- hoist this wave's A fragments (32 rows) into registers ----
  const int mg = wid >> 1, ng = wid & 1;         // GEMM1: 4M(32r) x 2N(16c)
  short8 areg[2][8];
  #pragma unroll
  for (int m = 0; m < 2; ++m)
    #pragma unroll
    for (int s = 0; s < 8; ++s) {
      const int r2 = mg * 32 + m * 16 + lrc;
      areg[m][s] = ws[r2 * 32 + ((s * 4 + lkc) ^ (r2 & 31))];
    }
  asm volatile("s_waitcnt lgkmcnt(0)" ::: "memory");
  __builtin_amdgcn_sched_barrier(0);
  __builtin_amdgcn_s_barrier();         // all waves done reading A from ws

  auto stage_w = [&](int ch, int buf) {
    const int kb = hb + ch * 32;
    #pragma unroll
    for (int i = 0; i < 2; ++i) {       // W1c: 32 rows x 256 k
      const int c = tid + i * 512;
      const int row = c >> 5, kc = c & 31;
      const unsigned short* gs = W1p + (size_t)(kb + row) * 256 +
                                 ((kc ^ (row & 31)) << 3);
      __builtin_amdgcn_global_load_lds(
          (const __attribute__((address_space(1))) u32*)gs,
          (__attribute__((address_space(3))) u32*)&ws[buf * 2048 + c], 16, 0, 0);
    }
    #pragma unroll
    for (int i = 0; i < 2; ++i) {       // W2c: 256 rows x 32 k (stride 2048)
      const int c = tid + i * 512;
      const int row = c >> 2, kc = c & 3;
      const int g = (kc ^ (row & 3) ^ ((row >> 2) & 3)) & 3;
      const unsigned short* gs = W2p + (size_t)row * 2048 + kb + (g << 3);
      __builtin_amdgcn_global_load_lds(
          (const __attribute__((address_space(1))) u32*)gs,
          (__attribute__((address_space(3))) u32*)&ws[buf * 2048 + 1024 + c],
          16, 0, 0);
    }
  };
  stage_w(0, 0);

  const int wr = wid >> 2, wc = wid & 3;         // GEMM2: 2x4 waves, 64x64
  f32x4 acc2[4][4];
  #pragma unroll
  for (int m = 0; m < 4; ++m)
    #pragma unroll
    for (int n = 0; n < 4; ++n) acc2[m][n] = (f32x4){0.f, 0.f, 0.f, 0.f};

  for (int ch = 0; ch < NCH; ++ch) {
    const int cur = ch & 1;
    const int wb = cur * 2048;
    asm volatile("s_waitcnt vmcnt(0)" ::: "memory");   // W(ch) landed (mine)
    __builtin_amdgcn_sched_barrier(0);
    __builtin_amdgcn_s_barrier();       // barrier A: W(ch) landed for ALL;
                                        // GEMM1/2(ch-1) reads of buf^1 done
    __builtin_amdgcn_sched_barrier(0);
    if (ch + 1 < NCH) stage_w(ch + 1, cur ^ 1);

    // ---- GEMM1: h = relu(A @ W1c^T + b1); A from regs, 8 bf reads ----
    f32x4 a1[2];
    a1[0] = (f32x4){0.f, 0.f, 0.f, 0.f};
    a1[1] = (f32x4){0.f, 0.f, 0.f, 0.f};
    const int cn1 = ng * 16 + lrc;
    #pragma unroll
    for (int s = 0; s < 8; ++s) {
      short8 bf = ws[wb + cn1 * 32 + ((s * 4 + lkc) ^ cn1)];
      a1[0] = __builtin_amdgcn_mfma_f32_16x16x32_bf16(areg[0][s], bf, a1[0], 0, 0, 0);
      a1[1] = __builtin_amdgcn_mfma_f32_16x16x32_bf16(areg[1][s], bf, a1[1], 0, 0, 0);
    }
    // bias + relu + bf16 -> h LDS (swizzled for GEMM2 reads)
    unsigned short* h16 = (unsigned short*)h8;
    #pragma unroll
    for (int m = 0; m < 2; ++m)
      #pragma unroll
      for (int j = 0; j < 4; ++j) {
        const int row = mg * 32 + m * 16 + lkc * 4 + j;
        const float v = fmaxf(a1[m][j] + b1f[ch * 32 + cn1], 0.f);
        const int g = ((cn1 >> 3) ^ (row & 3) ^ ((row >> 2) & 3)) & 3;
        h16[row * 32 + g * 8 + (cn1 & 7)] = f2b(v);
      }
    asm volatile("s_waitcnt lgkmcnt(0)" ::: "memory");
    __builtin_amdgcn_sched_barrier(0);
    __builtin_amdgcn_s_barrier();       // barrier B: h visible to all waves
    __builtin_amdgcn_sched_barrier(0);

    // ---- GEMM2: acc2 += h @ W2c^T (K=32) ----
    short8 af2[4], bf2[4];
    #pragma unroll
    for (int m = 0; m < 4; ++m) {
      const int r2 = wr * 64 + m * 16 + lrc;
      af2[m] = h8[r2 * 4 + ((lkc ^ (r2 & 3) ^ ((r2 >> 2) & 3)) & 3)];
    }
    #pragma unroll
    for (int n = 0; n < 4; ++n) {
      const int cn = wc * 64 + n * 16 + lrc;
      bf2[n] = ws[wb + 1024 + cn * 4 + ((lkc ^ (cn & 3) ^ ((cn >> 2) & 3)) & 3)];
    }
    #pragma unroll
    for (int m = 0; m < 4; ++m)
      #pragma unroll
      for (int n = 0; n < 4; ++n)
        acc2[m][n] = __builtin_amdgcn_mfma_f32_16x16x32_bf16(
            af2[m], bf2[n], acc2[m][n], 0, 0, 0);
  }

  // ---- direct fp32 epilogue (half 0 adds b2) ----
  const int r0 = lkc * 4;
  #pragma unroll
  for (int m = 0; m < 4; ++m) {
    const int gm = m0 + wr * 64 + m * 16 + r0;
    #pragma unroll
    for (int n = 0; n < 4; ++n) {
      const int gn = wc * 64 + n * 16 + lrc;
      const float bb = (half == 0) ? b2p[gn] : 0.f;
      #pragma unroll
      for (int j = 0; j < 4; ++j)
        Cf[(size_t)(gm + j) * 256 + gn] = acc2[m][n][j] + bb;
    }
  }
}

// ---------------------------------------------------------------------------
// Conv compression, K and V in one dispatch (blockIdx.z): z=0 reads g_tb
// (k proj) -> g_kc with null_k edge; z=1 reads g_ffh (v proj) -> g_vc.
__global__ __launch_bounds__(256) void compress2_k(
    const float* __restrict__ cw, const float* __restrict__ cb,
    const float* __restrict__ nk, const float* __restrict__ nv) {
  __shared__ float rows[32][256];       // 32 KB
  const int tc0 = 1 + blockIdx.x * 16;
  const int b = blockIdx.y;
  const int z = blockIdx.z;
  const int tid = threadIdx.x;
  const int o = tid;
  const int g = o >> 5;

  const unsigned short* srcbuf = z ? g_ffh : g_tb;
  const float* nul = z ? nv : nk;
  float* outb = (z ? g_vc : g_kc) + (size_t)b * Tkv * Dm;

  const int r0g = 2 * tc0 - 2;
  const unsigned short* src = srcbuf + ((size_t)b * Tt + r0g) * Dm;
  #pragma unroll
  for (int i = 0; i < 4; ++i) {
    const int c = tid + i * 256;        // 1024 chunks of 8
    const int row = c >> 5, off = (c & 31) * 8;
    short8 v = *(const short8*)(src + (size_t)row * 256 + off);
    #pragma unroll
    for (int j = 0; j < 8; ++j)
      rows[row][off + j] = b2f((unsigned short)v[j]);
  }

  float we[32], wo[32];
  {
    const float4* wp = (const float4*)(cw + o * 64);
    #pragma unroll
    for (int i = 0; i < 16; ++i) {
      float4 w4 = wp[i];
      we[i * 2 + 0] = w4.x; wo[i * 2 + 0] = w4.y;
      we[i * 2 + 1] = w4.z; wo[i * 2 + 1] = w4.w;
    }
  }
  const float bias = cb[o];
  if (blockIdx.x == 0) {                // edge rows j=0,1
    outb[o] = nul[b * Dm + o];
    outb[Dm + o] = bias;
  }
  __syncthreads();

  float* outp = outb + o;
  #pragma unroll
  for (int t = 0; t < 16; ++t) {
    const int lr = 2 * t;
    const float* p0 = &rows[lr][g * 32];
    const float* p1 = &rows[lr + 1][g * 32];
    float acc = bias;
    #pragma unroll
    for (int i4 = 0; i4 < 8; ++i4) {
      float4 a0 = *(const float4*)(p0 + i4 * 4);
      float4 a1 = *(const float4*)(p1 + i4 * 4);
      acc = fmaf(we[i4 * 4 + 0], a0.x, acc);
      acc = fmaf(we[i4 * 4 + 1], a0.y, acc);
      acc = fmaf(we[i4 * 4 + 2], a0.z, acc);
      acc = fmaf(we[i4 * 4 + 3], a0.w, acc);
      acc = fmaf(wo[i4 * 4 + 0], a1.x, acc);
      acc = fmaf(wo[i4 * 4 + 1], a1.y, acc);
      acc = fmaf(wo[i4 * 4 + 2], a1.z, acc);
      acc = fmaf(wo[i4 * 4 + 3], a1.w, acc);
    }
    outp[(size_t)(1 + tc0 + t) * Dm] = acc;
  }
}

// ---------------------------------------------------------------------------
// KV reduction stage 1/2 (validated).
__global__ __launch_bounds__(256) void kvout1_k() {
  __shared__ float kl[8][32];
  __shared__ float vl[8][32];
  const int bh = blockIdx.x;
  const int js = blockIdx.y;
  const int b = bh >> 3, h = bh & 7;
  const int j0 = js * 101;
  const int jend = (j0 + 101 < Tkv) ? j0 + 101 : Tkv;

  const int tid = threadIdx.x;
  const int lr = tid >> 5;
  const int lc = tid & 31;
  const int e = tid >> 3;
  const int d0 = (tid & 7) * 4;

  float a0 = 0.f, a1 = 0.f, a2 = 0.f, a3 = 0.f;
  const size_t base = (size_t)b * Tkv * Dm + h * 32;

  for (int jc = j0; jc < jend; jc += 8) {
    const int jr = jc + lr;
    if (jr < jend) {
      kl[lr][lc] = g_kc[base + (size_t)jr * Dm + lc];
      vl[lr][lc] = g_vc[base + (size_t)jr * Dm + lc];
    } else {
      kl[lr][lc] = 0.f;
      vl[lr][lc] = 0.f;
    }
    __syncthreads();
    #pragma unroll
    for (int r = 0; r < 8; ++r) {
      const float kf = kl[r][e];
      const float* vr = &vl[r][d0];
      a0 = fmaf(kf, vr[0], a0);
      a1 = fmaf(kf, vr[1], a1);
      a2 = fmaf(kf, vr[2], a2);
      a3 = fmaf(kf, vr[3], a3);
    }
    __syncthreads();
  }
  float* op = g_kvp + ((size_t)js * 80 + bh) * 1024 + e * 32 + d0;
  op[0] = a0; op[1] = a1; op[2] = a2; op[3] = a3;
}

__global__ __launch_bounds__(256) void kvout2_k() {
  const int bh = blockIdx.x;
  const int tid = threadIdx.x;
  const int e = tid >> 3;
  const int d0 = (tid & 7) * 4;
  float a0 = 0.f, a1 = 0.f, a2 = 0.f, a3 = 0.f;
  #pragma unroll
  for (int s = 0; s < JCH; ++s) {
    const float* p = g_kvp + ((size_t)s * 80 + bh) * 1024 + e * 32 + d0;
    a0 += p[0]; a1 += p[1]; a2 += p[2]; a3 += p[3];
  }
  float* op = g_kvm + (size_t)bh * 1024 + e * 32 + d0;
  op[0] = a0 * 0.0625f;
  op[1] = a1 * 0.0625f;
  op[2] = a2 * 0.0625f;
  op[3] = a3 * 0.0625f;
}

// ---------------------------------------------------------------------------
// W'[b,n,h*32+e] = sum_d kvm[b,h,e,d] * Wo[n,h*32+d]   (bf16 out)
__global__ __launch_bounds__(256) void wo2_k(int wooff) {
  const int n = blockIdx.x, b = blockIdx.y;
  const int he = threadIdx.x;
  const int h = he >> 5, e = he & 31;
  const float* kp = g_kvm + ((size_t)(b * Hh + h) * 32 + e) * 32;
  const unsigned short* wp = g_wb + wooff + (size_t)n * Dm + h * 32;
  float acc = 0.f;
  #pragma unroll
  for (int d = 0; d < 32; ++d) acc = fmaf(kp[d], b2f(wp[d]), acc);
  g_wo2[(size_t)b * 65536 + (size_t)n * Dm + he] = f2b(acc);
}

// ---------------------------------------------------------------------------
// x = LN(x + d1 [+ d2])*g + beta (fp32), writes bf16 shadow g_xb.
// If do_pos: also writes g_qkb = bf16(ln_out + pos).
__global__ __launch_bounds__(256) void ln_k(int did, int did2, const float* g,
                                            const float* beta, int do_pos) {
  const int lane = threadIdx.x & 63;
  const int wave = threadIdx.x >> 6;
  const size_t row = (size_t)blockIdx.x * 4 + wave;
  float4 xv = ((const float4*)g_x)[row * 64 + lane];
  float4 dv = ((const float4*)selbuf(did))[row * 64 + lane];
  float v[4] = {xv.x + dv.x, xv.y + dv.y, xv.z + dv.z, xv.w + dv.w};
  if (did2 >= 0) {
    float4 d2 = ((const float4*)selbuf(did2))[row * 64 + lane];
    v[0] += d2.x; v[1] += d2.y; v[2] += d2.z; v[3] += d2.w;
  }
  float sum = v[0] + v[1] + v[2] + v[3];
  float sq = v[0]*v[0] + v[1]*v[1] + v[2]*v[2] + v[3]*v[3];
  #pragma unroll
  for (int off = 32; off; off >>= 1) {
    sum += __shfl_xor(sum, off);
    sq  += __shfl_xor(sq, off);
  }
  const float mean = sum * (1.f / 256.f);
  const float var = sq * (1.f / 256.f) - mean * mean;
  const float rs = rsqrtf(var + 1e-5f);
  float4 gg = ((const float4*)g)[lane];
  float4 bb = ((const float4*)beta)[lane];
  float4 ov;
  ov.x = (v[0] - mean) * rs * gg.x + bb.x;
  ov.y = (v[1] - mean) * rs * gg.y + bb.y;
  ov.z = (v[2] - mean) * rs * gg.z + bb.z;
  ov.w = (v[3] - mean) * rs * gg.w + bb.w;
  ((float4*)g_x)[row * 64 + lane] = ov;
  short4v sv;
  sv[0] = (short)f2b(ov.x); sv[1] = (short)f2b(ov.y);
  sv[2] = (short)f2b(ov.z); sv[3] = (short)f2b(ov.w);
  *(short4v*)&g_xb[(row * 64 + lane) * 4] = sv;
  if (do_pos) {
    float4 pv = ((const float4*)g_pos)[row * 64 + lane];
    short4v qv;
    qv[0] = (short)f2b(ov.x + pv.x); qv[1] = (short)f2b(ov.y + pv.y);
    qv[2] = (short)f2b(ov.z + pv.z); qv[3] = (short)f2b(ov.w + pv.w);
    *(short4v*)&g_qkb[(row * 64 + lane) * 4] = qv;
  }
}

// ---------------------------------------------------------------------------
extern "C" void kernel_launch(void* const* d_in, const int* in_sizes, int n_in,
                              void* d_out, int out_size, void* d_ws, size_t ws_size,
                              hipStream_t stream) {
  const float* src  = (const float*)d_in[0];
  const float* pose = (const float*)d_in[1];
  const float* Wq   = (const float*)d_in[2];
  const float* Wk   = (const float*)d_in[3];
  const float* Wv   = (const float*)d_in[4];
  const float* Wo   = (const float*)d_in[5];
  const float* bo   = (const float*)d_in[6];
  const float* cw   = (const float*)d_in[7];
  const float* cb   = (const float*)d_in[8];
  const float* nk   = (const float*)d_in[9];
  const float* nv   = (const float*)d_in[10];
  const float* ln1g = (const float*)d_in[11];
  const float* ln1b = (const float*)d_in[12];
  const float* ln2g = (const float*)d_in[13];
  const float* ln2b = (const float*)d_in[14];
  const float* W1   = (const float*)d_in[15];
  const float* b1   = (const float*)d_in[16];
  const float* W2   = (const float*)d_in[17];
  const float* b2   = (const float*)d_in[18];

  const int MT = Bsz * Tt;        // 16000
  const dim3 tgrid(Tt / 32, Dm / 32, Bsz);

  // g_wb layout: per-layer [Wk|Wq] at l*131072; then Wv, Wo, W1, W2.
  const int OV = 262144, OO = 393216, O1 = 524288, O2 = 1572864;
  wconv_all_k<<<10240, 256, 0, stream>>>(Wk, Wq, Wv, Wo, W1, W2);
  trans_in2_k<<<tgrid, 256, 0, stream>>>(src, pose);  // x, xb, pos, qkb

  const int MB = MT / 128;  // 125 m-blocks
  for (int l = 0; l < 2; ++l) {
    const float* bo_l = bo + (size_t)l * Dm;
    const float* cw_l = cw + (size_t)l * Dm * 64;
    const float* cb_l = cb + (size_t)l * Dm;
    const float* nk_l = nk + (size_t)l * Bsz * Dm;
    const float* nv_l = nv + (size_t)l * Bsz * Dm;
    const float* b1_l = b1 + (size_t)l * FFd;
    const float* b2_l = b2 + (size_t)l * Dm;
    const int wkq = l * 131072;
    const int wv = OV + l * 65536, wo = OO + l * 65536;
    const int w1 = O1 + l * 524288, w2 = O2 + l * 524288;

    // [k|q] = qkb @ [Wk|Wq]^T : k -> tb, q -> qb (DUAL, NB=8, grid 1000)
    gemm2_k<64, true, false, false, false, true><<<8 * MB, 256, 0, stream>>>(
        1, wkq, nullptr, 2, 4, 8, MT, 512, Dm);
    // v = xb @ Wv^T -> ffh (scratch)  (NB=4, grid 500)
    gemm2_k<64, false, false, false, false, true><<<4 * MB, 256, 0, stream>>>(
        0, wv, nullptr, 3, 3, 4, MT, Dm, Dm);
    // compress K (tb->kc) and V (ffh->vc) in one dispatch
    compress2_k<<<dim3(50, Bsz, 2), 256, 0, stream>>>(cw_l, cb_l, nk_l, nv_l);
    // kvm = (1/16) kc^T vc
    kvout1_k<<<dim3(Bsz * Hh, JCH), 256, 0, stream>>>();
    kvout2_k<<<Bsz * Hh, 256, 0, stream>>>();
    // W' = kvm (×) Wo  (per-b fused attn+Wo weights)
    wo2_k<<<dim3(Dm, Bsz), 256, 0, stream>>>(wo);
    // t = qb @ W'^T + bo (fp32, per-b, PERB; grid 520)
    gemm2_k<64, false, true, false, true, false><<<Bsz * 13 * 4, 256, 0, stream>>>(
        4, 0, bo_l, 2, 2, 4, MT, Dm, Dm);
    ln_k<<<MT / 4, 256, 0, stream>>>(2, -1, ln1g + l * Dm, ln1b + l * Dm, 0);

    // Fused FF v3: half0 -> g_qk (+b2), half1 -> g_t  [grid 250, 1 blk/CU]
    gemmf_k<<<250, 512, 0, stream>>>(0, w1, w2, b1_l, b2_l);
    // LN2 sums both FF halves; layer 0 fused with next layer's pos-add.
    ln_k<<<MT / 4, 256, 0, stream>>>(1, 2, ln2g + l * Dm, ln2b + l * Dm,
                                     l == 0 ? 1 : 0);
  }

  trans_out_k<<<tgrid, 256, 0, stream>>>((float*)d_out);
}

// Round 10
// 362.073 us; speedup vs baseline: 1.4137x; 1.0293x over previous
//
#include <hip/hip_runtime.h>
#include <math.h>

typedef __attribute__((ext_vector_type(8))) short short8;   // 8 bf16
typedef __attribute__((ext_vector_type(4))) short short4v;  // 4 bf16
typedef __attribute__((ext_vector_type(4))) float f32x4;
typedef unsigned int u32;

constexpr int Bsz = 10;
constexpr int Dm  = 256;
constexpr int Hh  = 8;
constexpr int Tt  = 1600;
constexpr int FFd = 2048;
constexpr int Tkv = 802;   // 1 null + 801 compressed
constexpr int JCH = 8;     // j-splits for kv reduction
constexpr size_t Fsz  = (size_t)Bsz * Tt * Dm;    // 4,096,000
constexpr size_t PAD  = 65536;
constexpr size_t KVsz = (size_t)Bsz * Tkv * Dm;   // 2,053,120
constexpr size_t FHsz = (size_t)Bsz * Tt * FFd;   // 32,768,000
constexpr size_t WBsz = 2621440;                  // all weights, bf16

// Static device scratch; referenced ONLY from device code.
__device__ float g_x[Fsz];                        // residual stream fp32
__device__ float g_qk[Fsz];                       // FF q0 out (LN2 d1)
__device__ float g_t[Fsz];                        // Wo out / FF q1 (LN2 d2)
__device__ float g_kc[KVsz];                      // compressed K
__device__ float g_vc[KVsz];                      // compressed V
__device__ float g_kvm[(size_t)Bsz * Hh * 32 * 32];
__device__ float g_kvp[(size_t)JCH * Bsz * Hh * 32 * 32];
__device__ float g_pos[Fsz];                      // transposed pos fp32
__device__ unsigned short g_xb[Fsz + PAD];        // bf16 shadow of x
__device__ unsigned short g_qkb[Fsz + PAD];       // bf16 x+pos
__device__ unsigned short g_tb[Fsz + PAD];        // bf16 k projection
__device__ unsigned short g_qb[Fsz + PAD];        // bf16 q projection
// v-proj scratch early in layer; FF quarters 2/3 reuse it as TWO f32 buffers.
__device__ __attribute__((aligned(16))) unsigned short g_ffh[FHsz + PAD];
__device__ unsigned short g_wb[WBsz];             // bf16 weights
__device__ unsigned short g_wo2[(size_t)Bsz * Dm * Dm];  // per-b fused kvm*Wo

__device__ __forceinline__ float* selbuf(int id) {
  switch (id) {
    case 0: return g_x;
    case 1: return g_qk;
    case 2: return g_t;
    case 3: return g_kc;
    case 4: return g_vc;
    case 5: return g_kvm;
    case 6: return (float*)g_ffh;
    default: return (float*)g_ffh + Fsz;
  }
}
__device__ __forceinline__ unsigned short* selbufb(int id) {
  switch (id) {
    case 0: return g_xb;
    case 1: return g_qkb;
    case 2: return g_tb;
    case 3: return g_ffh;
    default: return g_qb;
  }
}

// fp32 -> bf16 (RNE)
__device__ __forceinline__ unsigned short f2b(float x) {
  unsigned int u = __float_as_uint(x);
  u += 0x7FFFu + ((u >> 16) & 1u);
  return (unsigned short)(u >> 16);
}
__device__ __forceinline__ float b2f(unsigned short u) {
  return __uint_as_float(((unsigned int)u) << 16);
}

// ---------------------------------------------------------------------------
// ALL weight conversions in one dispatch. g_wb layout:
// [l0:Wk|Wq][l1:Wk|Wq] | Wv(l0,l1) | Wo(l0,l1) | W1(l0,l1) | W2(l0,l1)
__global__ __launch_bounds__(256) void wconv_all_k(
    const float* __restrict__ Wk, const float* __restrict__ Wq,
    const float* __restrict__ Wv, const float* __restrict__ Wo,
    const float* __restrict__ W1, const float* __restrict__ W2) {
  const int i = blockIdx.x * 256 + threadIdx.x;   // < 2,621,440
  float v;
  if (i < 262144) {
    const int l = i >> 17, r = i & 131071;
    v = (r < 65536) ? Wk[l * 65536 + r] : Wq[l * 65536 + (r - 65536)];
  } else if (i < 393216) {
    v = Wv[i - 262144];
  } else if (i < 524288) {
    v = Wo[i - 393216];
  } else if (i < 1572864) {
    v = W1[i - 524288];
  } else {
    v = W2[i - 1572864];
  }
  g_wb[i] = f2b(v);
}

// ---------------------------------------------------------------------------
// Fused input transpose + pos-add: src,pose [B,D,T] -> g_x, g_xb, g_pos,
// g_qkb = bf16(x+pos).
__global__ __launch_bounds__(256) void trans_in2_k(const float* __restrict__ src,
                                                   const float* __restrict__ pose) {
  __shared__ float ts[32][33];
  __shared__ float tp[32][33];
  const int tx = threadIdx.x & 31, ty = threadIdx.x >> 5;
  const int t0 = blockIdx.x * 32, d0 = blockIdx.y * 32, b = blockIdx.z;
  #pragma unroll
  for (int i = ty; i < 32; i += 8) {
    const size_t gi = ((size_t)(b * Dm + d0 + i)) * Tt + t0 + tx;
    ts[i][tx] = src[gi];
    tp[i][tx] = pose[gi];
  }
  __syncthreads();
  #pragma unroll
  for (int i = ty; i < 32; i += 8) {
    const size_t idx = ((size_t)(b * Tt + t0 + i)) * Dm + d0 + tx;
    const float s = ts[tx][i], p = tp[tx][i];
    g_x[idx] = s;
    g_pos[idx] = p;
    g_xb[idx] = f2b(s);
    g_qkb[idx] = f2b(s + p);
  }
}

__global__ __launch_bounds__(256) void trans_out_k(float* out) {
  __shared__ float tile[32][33];
  const int tx = threadIdx.x & 31, ty = threadIdx.x >> 5;
  const int t0 = blockIdx.x * 32, d0 = blockIdx.y * 32, b = blockIdx.z;
  #pragma unroll
  for (int i = ty; i < 32; i += 8)
    tile[i][tx] = g_x[((size_t)(b * Tt + t0 + i)) * Dm + d0 + tx];
  __syncthreads();
  #pragma unroll
  for (int i = ty; i < 32; i += 8)
    out[((size_t)(b * Dm + d0 + i)) * Tt + t0 + tx] = tile[tx][i];
}

// ---------------------------------------------------------------------------
// MFMA GEMM for K=256 mid-size-grid cases (KQ, V, attn-out): BM=128, BN=64,
// BK=64; 4 waves (2x2). 3 LDS buffers, ONE barrier per K-step, stage
// hoisted before compute (round-4 structure). LDS 72KB -> 2 blocks/CU.
// DUAL (N=512 merged KQ): n0<256 -> Cid, n0>=256 -> C2id, stride 256.
// PERB: per-batch weights g_wo2 (13 m-blocks x NB per b), guarded stores.
template<int BN, bool DUAL, bool PERB, bool RELU, bool BIAS, bool CBF16>
__global__ __launch_bounds__(256) void gemm2_k(
    int Aid, int woff, const float* __restrict__ bias, int Cid, int C2id,
    int NB, int M, int N, int K) {
  constexpr int BM = 128, BK = 64;
  constexpr int ACH = BM * 8;           // 1024 short8 (16 KB)
  constexpr int BCH = BN * 8;           // 512 short8 (8 KB)
  constexpr int NW = BN / 32;           // n-frags per wave
  __shared__ short8 As8[3][ACH];
  __shared__ short8 Bs8[3][BCH];
  const int tid = threadIdx.x;
  const int lane = tid & 63, wid = tid >> 6;
  const int wr = wid >> 1, wc = wid & 1;

  // XCD-aware bijective remap (m204).
  const int nwg = gridDim.x;
  const int bid = blockIdx.x;
  const int q = nwg >> 3, r = nwg & 7;
  const int xcd = bid & 7, seq = bid >> 3;
  const int wgid = (xcd < r ? xcd * (q + 1) : r * (q + 1) + (xcd - r) * q) + seq;

  int m0, n0, mlim;
  const unsigned short* W16;
  if constexpr (PERB) {
    const int per = 13 * NB;
    const int b = wgid / per;
    const int rem = wgid - b * per;
    m0 = b * Tt + (rem / NB) * BM;
    n0 = (rem % NB) * BN;
    mlim = b * Tt + Tt;
    W16 = g_wo2 + (size_t)b * 65536;
  } else {
    m0 = (wgid / NB) * BM;
    n0 = (wgid % NB) * BN;
    mlim = M;
    W16 = g_wb + woff;
  }

  const unsigned short* A16 = selbufb(Aid);
  const bool second = DUAL && (n0 >= 256);
  float* Cf = selbuf(second ? C2id : Cid);
  unsigned short* C16 = selbufb(second ? C2id : Cid);
  const int gn0 = second ? n0 - 256 : n0;
  const int cstride = DUAL ? 256 : N;

  f32x4 acc[4][NW];
  #pragma unroll
  for (int m = 0; m < 4; ++m)
    #pragma unroll
    for (int n = 0; n < NW; ++n) acc[m][n] = (f32x4){0.f, 0.f, 0.f, 0.f};

  const int lkc = lane >> 4, lrc = lane & 15;

  auto stage = [&](int t, int buf) {
    const int k0 = t * BK;
    #pragma unroll
    for (int i = 0; i < ACH / 256; ++i) {
      const int c = tid + i * 256;
      const int row = c >> 3, kc = c & 7;
      const unsigned short* gs = A16 + (size_t)(m0 + row) * K + k0 +
                                 ((kc ^ (row & 7)) << 3);
      __builtin_amdgcn_global_load_lds(
          (const __attribute__((address_space(1))) u32*)gs,
          (__attribute__((address_space(3))) u32*)&As8[buf][c], 16, 0, 0);
    }
    #pragma unroll
    for (int i = 0; i < BCH / 256; ++i) {
      const int c = tid + i * 256;
      const int row = c >> 3, kc = c & 7;
      const unsigned short* gs = W16 + (size_t)(n0 + row) * K + k0 +
                                 ((kc ^ (row & 7)) << 3);
      __builtin_amdgcn_global_load_lds(
          (const __attribute__((address_space(1))) u32*)gs,
          (__attribute__((address_space(3))) u32*)&Bs8[buf][c], 16, 0, 0);
    }
  };

  const int nt = K / BK;
  stage(0, 0);
  if (nt > 1) stage(1, 1);
  int cur = 0, nxt = 2;                 // nxt = (t+2)%3 target
  for (int t = 0; t < nt; ++t) {
    if (t + 1 < nt) {
      asm volatile("s_waitcnt vmcnt(6)" ::: "memory");
    } else {
      asm volatile("s_waitcnt vmcnt(0)" ::: "memory");
    }
    __builtin_amdgcn_sched_barrier(0);
    __builtin_amdgcn_s_barrier();       // buf[cur] landed for ALL waves;
                                        // ALL waves done reading buf[nxt]
    __builtin_amdgcn_sched_barrier(0);
    if (t + 2 < nt) stage(t + 2, nxt);  // overlaps with compute below
    #pragma unroll
    for (int kk = 0; kk < 2; ++kk) {
      short8 af[4], bf[NW];
      #pragma unroll
      for (int m = 0; m < 4; ++m) {
        const int r2 = wr * 64 + m * 16 + lrc;
        af[m] = As8[cur][r2 * 8 + ((kk * 4 + lkc) ^ (r2 & 7))];
      }
      #pragma unroll
      for (int n = 0; n < NW; ++n) {
        const int cn = wc * (BN / 2) + n * 16 + lrc;
        bf[n] = Bs8[cur][cn * 8 + ((kk * 4 + lkc) ^ (cn & 7))];
      }
      #pragma unroll
      for (int m = 0; m < 4; ++m)
        #pragma unroll
        for (int n = 0; n < NW; ++n)
          acc[m][n] = __builtin_amdgcn_mfma_f32_16x16x32_bf16(
              af[m], bf[n], acc[m][n], 0, 0, 0);
    }
    cur = (cur == 2) ? 0 : cur + 1;
    nxt = (nxt == 2) ? 0 : nxt + 1;
  }

  // ---- LDS-staged epilogue: deposit acc, then coalesced row stores ----
  constexpr int CSTR = (BN == 64) ? BN + 4 : BN;
  float* ldsC = (float*)&As8[0][0];
  {
    asm volatile("s_waitcnt vmcnt(0)" ::: "memory");
    __builtin_amdgcn_s_barrier();       // all waves done reading As8/Bs8
    const int r0 = lkc * 4;
    #pragma unroll
    for (int m = 0; m < 4; ++m)
      #pragma unroll
      for (int n = 0; n < NW; ++n) {
        const int col = wc * (BN / 2) + n * 16 + lrc;
        #pragma unroll
        for (int j = 0; j < 4; ++j)
          ldsC[(wr * 64 + m * 16 + r0 + j) * CSTR + col] = acc[m][n][j];
      }
    __syncthreads();
  }
  if constexpr (CBF16) {
    constexpr int CH = BM * BN / 8;     // short8 chunks
    #pragma unroll
    for (int i = 0; i < CH / 256; ++i) {
      const int c = tid + i * 256;
      const int rowl = c / (BN / 8), col8 = (c % (BN / 8)) * 8;
      if (PERB && m0 + rowl >= mlim) continue;
      short8 v;
      #pragma unroll
      for (int j = 0; j < 8; ++j) {
        float x = ldsC[rowl * CSTR + col8 + j];
        if (BIAS) x += bias[gn0 + col8 + j];
        if (RELU) x = fmaxf(x, 0.f);
        v[j] = (short)f2b(x);
      }
      *(short8*)(C16 + (size_t)(m0 + rowl) * cstride + gn0 + col8) = v;
    }
  } else {
    constexpr int CH = BM * BN / 4;     // float4 chunks
    #pragma unroll
    for (int i = 0; i < CH / 256; ++i) {
      const int c = tid + i * 256;
      const int rowl = c / (BN / 4), col4 = (c % (BN / 4)) * 4;
      if (PERB && m0 + rowl >= mlim) continue;
      float4 v;
      float* pv = &v.x;
      #pragma unroll
      for (int j = 0; j < 4; ++j) {
        float x = ldsC[rowl * CSTR + col4 + j];
        if (BIAS) x += bias[gn0 + col4 + j];
        if (RELU) x = fmaxf(x, 0.f);
        pv[j] = x;
      }
      *(float4*)(Cf + (size_t)(m0 + rowl) * cstride + gn0 + col4) = v;
    }
  }
}

// ---------------------------------------------------------------------------
// FUSED FF v4 (round-10): v3's body (launch_bounds(512,1), VGPR free -> 92,
// no spill) + r8's QUARTER split (grid 500 = 125 m-blocks x 4 quarters,
// NCH=16). v3 diagnosis: 73us at Occupancy 20% -- grid 250 = 1 block/CU,
// everything latency-serial. v3's resources ALREADY permit 2 blocks/CU
// (LDS 75776x2 <= 160KB, VGPR 92 <= 128 -> 4 waves/SIMD); only the grid
// prevented it. Quarter split doubles residency (cross-block TLP hides the
// per-chunk serial chain) and halves the per-block chain. W-fetch volume
// invariant (each W element read by 125 blocks either way).
// q0 -> g_qk (+b2), q1 -> g_t, q2/q3 -> f32 views of g_ffh; ln2 sums 4
// (r8-validated path). r8's failure was the forced (512,4) VGPR cap, NOT
// the split -- do not add a waves-per-EU bound here.
__global__ __launch_bounds__(512, 1) void gemmf_k(
    int Aid, int w1off, int w2off, const float* __restrict__ b1p,
    const float* __restrict__ b2p) {
  constexpr int BM = 128, NCH = 16;     // 16 chunks x 32 hidden = 512
  __shared__ short8 ws[4096];           // 64 KB: A (prologue) then W dbuf:
                                        // [buf*2048 + w1c:1024 | w2c:1024]
  __shared__ short8 h8[512];            // 8 KB: h 128x32 bf16 (swizzled)
  __shared__ float b1f[512];            // 2 KB
  const int tid = threadIdx.x;
  const int lane = tid & 63, wid = tid >> 6;     // 8 waves
  const int lkc = lane >> 4, lrc = lane & 15;
  const int nwg = gridDim.x, bid = blockIdx.x;
  const int q = nwg >> 3, r = nwg & 7;
  const int xcd = bid & 7, seq = bid >> 3;
  const int wgid = (xcd < r ? xcd * (q + 1) : r * (q + 1) + (xcd - r) * q) + seq;
  const int qd = wgid / 125;            // hidden quarter 0..3
  const int m0 = (wgid - qd * 125) * BM;
  const int hb = qd * 512;              // hidden base
  const unsigned short* A16 = selbufb(Aid);
  const unsigned short* W1p = g_wb + w1off;
  const unsigned short* W2p = g_wb + w2off;
  float* Cf;
  if (qd == 0) Cf = g_qk;
  else if (qd == 1) Cf = g_t;
  else Cf = (float*)g_ffh + (size_t)(qd - 2) * Fsz;

  // ---- prologue: stage A (8/thr) + b1 (1/thr) into LDS ----
  #pragma unroll
  for (int i = 0; i < 8; ++i) {
    const int c = tid + i * 512;
    const int row = c >> 5, kc = c & 31;
    const unsigned short* gs = A16 + (size_t)(m0 + row) * 256 +
                               ((kc ^ (row & 31)) << 3);
    __builtin_amdgcn_global_load_lds(
        (const __attribute__((address_space(1))) u32*)gs,
        (__attribute__((address_space(3))) u32*)&ws[c], 16, 0, 0);
  }
  __builtin_amdgcn_global_load_lds(
      (const __attribute__((address_space(1))) u32*)(b1p + hb + tid),
      (__attribute__((address_space(3))) u32*)&b1f[tid], 4, 0, 0);
  asm volatile("s_waitcnt vmcnt(0)" ::: "memory");
  __builtin_amdgcn_sched_barrier(0);
  __builtin_amdgcn_s_barrier();

  // ---- hoist this wave's A fragments (32 rows) into registers ----
  const int mg = wid >> 1, ng = wid & 1;         // GEMM1: 4M(32r) x 2N(16c)
  short8 areg[2][8];
  #pragma unroll
  for (int m = 0; m < 2; ++m)
    #pragma unroll
    for (int s = 0; s < 8; ++s) {
      const int r2 = mg * 32 + m * 16 + lrc;
      areg[m][s] = ws[r2 * 32 + ((s * 4 + lkc) ^ (r2 & 31))];
    }
  asm volatile("s_waitcnt lgkmcnt(0)" ::: "memory");
  __builtin_amdgcn_sched_barrier(0);
  __builtin_amdgcn_s_barrier();         // all waves done reading A from ws

  auto stage_w = [&](int ch, int buf) {
    const int kb = hb + ch * 32;
    #pragma unroll
    for (int i = 0; i < 2; ++i) {       // W1c: 32 rows x 256 k
      const int c = tid + i * 512;
      const int row = c >> 5, kc = c & 31;
      const unsigned short* gs = W1p + (size_t)(kb + row) * 256 +
                                 ((kc ^ (row & 31)) << 3);
      __builtin_amdgcn_global_load_lds(
          (const __attribute__((address_space(1))) u32*)gs,
          (__attribute__((address_space(3))) u32*)&ws[buf * 2048 + c], 16, 0, 0);
    }
    #pragma unroll
    for (int i = 0; i < 2; ++i) {       // W2c: 256 rows x 32 k (stride 2048)
      const int c = tid + i * 512;
      const int row = c >> 2, kc = c & 3;
      const int g = (kc ^ (row & 3) ^ ((row >> 2) & 3)) & 3;
      const unsigned short* gs = W2p + (size_t)row * 2048 + kb + (g << 3);
      __builtin_amdgcn_global_load_lds(
          (const __attribute__((address_space(1))) u32*)gs,
          (__attribute__((address_space(3))) u32*)&ws[buf * 2048 + 1024 + c],
          16, 0, 0);
    }
  };
  stage_w(0, 0);

  const int wr = wid >> 2, wc = wid & 3;         // GEMM2: 2x4 waves, 64x64
  f32x4 acc2[4][4];
  #pragma unroll
  for (int m = 0; m < 4; ++m)
    #pragma unroll
    for (int n = 0; n < 4; ++n) acc2[m][n] = (f32x4){0.f, 0.f, 0.f, 0.f};

  for (int ch = 0; ch < NCH; ++ch) {
    const int cur = ch & 1;
    const int wb = cur * 2048;
    asm volatile("s_waitcnt vmcnt(0)" ::: "memory");   // W(ch) landed (mine)
    __builtin_amdgcn_sched_barrier(0);
    __builtin_amdgcn_s_barrier();       // barrier A: W(ch) landed for ALL;
                                        // GEMM1/2(ch-1) reads of buf^1 done
    __builtin_amdgcn_sched_barrier(0);
    if (ch + 1 < NCH) stage_w(ch + 1, cur ^ 1);

    // ---- GEMM1: h = relu(A @ W1c^T + b1); A from regs, 8 bf reads ----
    f32x4 a1[2];
    a1[0] = (f32x4){0.f, 0.f, 0.f, 0.f};
    a1[1] = (f32x4){0.f, 0.f, 0.f, 0.f};
    const int cn1 = ng * 16 + lrc;
    #pragma unroll
    for (int s = 0; s < 8; ++s) {
      short8 bf = ws[wb + cn1 * 32 + ((s * 4 + lkc) ^ cn1)];
      a1[0] = __builtin_amdgcn_mfma_f32_16x16x32_bf16(areg[0][s], bf, a1[0], 0, 0, 0);
      a1[1] = __builtin_amdgcn_mfma_f32_16x16x32_bf16(areg[1][s], bf, a1[1], 0, 0, 0);
    }
    // bias + relu + bf16 -> h LDS (swizzled for GEMM2 reads)
    unsigned short* h16 = (unsigned short*)h8;
    #pragma unroll
    for (int m = 0; m < 2; ++m)
      #pragma unroll
      for (int j = 0; j < 4; ++j) {
        const int row = mg * 32 + m * 16 + lkc * 4 + j;
        const float v = fmaxf(a1[m][j] + b1f[ch * 32 + cn1], 0.f);
        const int g = ((cn1 >> 3) ^ (row & 3) ^ ((row >> 2) & 3)) & 3;
        h16[row * 32 + g * 8 + (cn1 & 7)] = f2b(v);
      }
    asm volatile("s_waitcnt lgkmcnt(0)" ::: "memory");
    __builtin_amdgcn_sched_barrier(0);
    __builtin_amdgcn_s_barrier();       // barrier B: h visible to all waves
    __builtin_amdgcn_sched_barrier(0);

    // ---- GEMM2: acc2 += h @ W2c^T (K=32) ----
    short8 af2[4], bf2[4];
    #pragma unroll
    for (int m = 0; m < 4; ++m) {
      const int r2 = wr * 64 + m * 16 + lrc;
      af2[m] = h8[r2 * 4 + ((lkc ^ (r2 & 3) ^ ((r2 >> 2) & 3)) & 3)];
    }
    #pragma unroll
    for (int n = 0; n < 4; ++n) {
      const int cn = wc * 64 + n * 16 + lrc;
      bf2[n] = ws[wb + 1024 + cn * 4 + ((lkc ^ (cn & 3) ^ ((cn >> 2) & 3)) & 3)];
    }
    #pragma unroll
    for (int m = 0; m < 4; ++m)
      #pragma unroll
      for (int n = 0; n < 4; ++n)
        acc2[m][n] = __builtin_amdgcn_mfma_f32_16x16x32_bf16(
            af2[m], bf2[n], acc2[m][n], 0, 0, 0);
  }

  // ---- direct fp32 epilogue (quarter 0 adds b2) ----
  const int r0 = lkc * 4;
  #pragma unroll
  for (int m = 0; m < 4; ++m) {
    const int gm = m0 + wr * 64 + m * 16 + r0;
    #pragma unroll
    for (int n = 0; n < 4; ++n) {
      const int gn = wc * 64 + n * 16 + lrc;
      const float bb = (qd == 0) ? b2p[gn] : 0.f;
      #pragma unroll
      for (int j = 0; j < 4; ++j)
        Cf[(size_t)(gm + j) * 256 + gn] = acc2[m][n][j] + bb;
    }
  }
}

// ---------------------------------------------------------------------------
// Conv compression, K and V in one dispatch (blockIdx.z): z=0 reads g_tb
// (k proj) -> g_kc with null_k edge; z=1 reads g_ffh (v proj) -> g_vc.
__global__ __launch_bounds__(256) void compress2_k(
    const float* __restrict__ cw, const float* __restrict__ cb,
    const float* __restrict__ nk, const float* __restrict__ nv) {
  __shared__ float rows[32][256];       // 32 KB
  const int tc0 = 1 + blockIdx.x * 16;
  const int b = blockIdx.y;
  const int z = blockIdx.z;
  const int tid = threadIdx.x;
  const int o = tid;
  const int g = o >> 5;

  const unsigned short* srcbuf = z ? g_ffh : g_tb;
  const float* nul = z ? nv : nk;
  float* outb = (z ? g_vc : g_kc) + (size_t)b * Tkv * Dm;

  const int r0g = 2 * tc0 - 2;
  const unsigned short* src = srcbuf + ((size_t)b * Tt + r0g) * Dm;
  #pragma unroll
  for (int i = 0; i < 4; ++i) {
    const int c = tid + i * 256;        // 1024 chunks of 8
    const int row = c >> 5, off = (c & 31) * 8;
    short8 v = *(const short8*)(src + (size_t)row * 256 + off);
    #pragma unroll
    for (int j = 0; j < 8; ++j)
      rows[row][off + j] = b2f((unsigned short)v[j]);
  }

  float we[32], wo[32];
  {
    const float4* wp = (const float4*)(cw + o * 64);
    #pragma unroll
    for (int i = 0; i < 16; ++i) {
      float4 w4 = wp[i];
      we[i * 2 + 0] = w4.x; wo[i * 2 + 0] = w4.y;
      we[i * 2 + 1] = w4.z; wo[i * 2 + 1] = w4.w;
    }
  }
  const float bias = cb[o];
  if (blockIdx.x == 0) {                // edge rows j=0,1
    outb[o] = nul[b * Dm + o];
    outb[Dm + o] = bias;
  }
  __syncthreads();

  float* outp = outb + o;
  #pragma unroll
  for (int t = 0; t < 16; ++t) {
    const int lr = 2 * t;
    const float* p0 = &rows[lr][g * 32];
    const float* p1 = &rows[lr + 1][g * 32];
    float acc = bias;
    #pragma unroll
    for (int i4 = 0; i4 < 8; ++i4) {
      float4 a0 = *(const float4*)(p0 + i4 * 4);
      float4 a1 = *(const float4*)(p1 + i4 * 4);
      acc = fmaf(we[i4 * 4 + 0], a0.x, acc);
      acc = fmaf(we[i4 * 4 + 1], a0.y, acc);
      acc = fmaf(we[i4 * 4 + 2], a0.z, acc);
      acc = fmaf(we[i4 * 4 + 3], a0.w, acc);
      acc = fmaf(wo[i4 * 4 + 0], a1.x, acc);
      acc = fmaf(wo[i4 * 4 + 1], a1.y, acc);
      acc = fmaf(wo[i4 * 4 + 2], a1.z, acc);
      acc = fmaf(wo[i4 * 4 + 3], a1.w, acc);
    }
    outp[(size_t)(1 + tc0 + t) * Dm] = acc;
  }
}

// ---------------------------------------------------------------------------
// KV reduction stage 1/2 (validated).
__global__ __launch_bounds__(256) void kvout1_k() {
  __shared__ float kl[8][32];
  __shared__ float vl[8][32];
  const int bh = blockIdx.x;
  const int js = blockIdx.y;
  const int b = bh >> 3, h = bh & 7;
  const int j0 = js * 101;
  const int jend = (j0 + 101 < Tkv) ? j0 + 101 : Tkv;

  const int tid = threadIdx.x;
  const int lr = tid >> 5;
  const int lc = tid & 31;
  const int e = tid >> 3;
  const int d0 = (tid & 7) * 4;

  float a0 = 0.f, a1 = 0.f, a2 = 0.f, a3 = 0.f;
  const size_t base = (size_t)b * Tkv * Dm + h * 32;

  for (int jc = j0; jc < jend; jc += 8) {
    const int jr = jc + lr;
    if (jr < jend) {
      kl[lr][lc] = g_kc[base + (size_t)jr * Dm + lc];
      vl[lr][lc] = g_vc[base + (size_t)jr * Dm + lc];
    } else {
      kl[lr][lc] = 0.f;
      vl[lr][lc] = 0.f;
    }
    __syncthreads();
    #pragma unroll
    for (int r = 0; r < 8; ++r) {
      const float kf = kl[r][e];
      const float* vr = &vl[r][d0];
      a0 = fmaf(kf, vr[0], a0);
      a1 = fmaf(kf, vr[1], a1);
      a2 = fmaf(kf, vr[2], a2);
      a3 = fmaf(kf, vr[3], a3);
    }
    __syncthreads();
  }
  float* op = g_kvp + ((size_t)js * 80 + bh) * 1024 + e * 32 + d0;
  op[0] = a0; op[1] = a1; op[2] = a2; op[3] = a3;
}

__global__ __launch_bounds__(256) void kvout2_k() {
  const int bh = blockIdx.x;
  const int tid = threadIdx.x;
  const int e = tid >> 3;
  const int d0 = (tid & 7) * 4;
  float a0 = 0.f, a1 = 0.f, a2 = 0.f, a3 = 0.f;
  #pragma unroll
  for (int s = 0; s < JCH; ++s) {
    const float* p = g_kvp + ((size_t)s * 80 + bh) * 1024 + e * 32 + d0;
    a0 += p[0]; a1 += p[1]; a2 += p[2]; a3 += p[3];
  }
  float* op = g_kvm + (size_t)bh * 1024 + e * 32 + d0;
  op[0] = a0 * 0.0625f;
  op[1] = a1 * 0.0625f;
  op[2] = a2 * 0.0625f;
  op[3] = a3 * 0.0625f;
}

// ---------------------------------------------------------------------------
// W'[b,n,h*32+e] = sum_d kvm[b,h,e,d] * Wo[n,h*32+d]   (bf16 out)
__global__ __launch_bounds__(256) void wo2_k(int wooff) {
  const int n = blockIdx.x, b = blockIdx.y;
  const int he = threadIdx.x;
  const int h = he >> 5, e = he & 31;
  const float* kp = g_kvm + ((size_t)(b * Hh + h) * 32 + e) * 32;
  const unsigned short* wp = g_wb + wooff + (size_t)n * Dm + h * 32;
  float acc = 0.f;
  #pragma unroll
  for (int d = 0; d < 32; ++d) acc = fmaf(kp[d], b2f(wp[d]), acc);
  g_wo2[(size_t)b * 65536 + (size_t)n * Dm + he] = f2b(acc);
}

// ---------------------------------------------------------------------------
// x = LN(x + d1 [+ d2 + d3 + d4])*g + beta (fp32), writes bf16 shadow g_xb.
// If do_pos: also writes g_qkb = bf16(ln_out + pos).
__global__ __launch_bounds__(256) void ln_k(int did, int did2, int did3,
                                            int did4, const float* g,
                                            const float* beta, int do_pos) {
  const int lane = threadIdx.x & 63;
  const int wave = threadIdx.x >> 6;
  const size_t row = (size_t)blockIdx.x * 4 + wave;
  float4 xv = ((const float4*)g_x)[row * 64 + lane];
  float4 dv = ((const float4*)selbuf(did))[row * 64 + lane];
  float v[4] = {xv.x + dv.x, xv.y + dv.y, xv.z + dv.z, xv.w + dv.w};
  if (did2 >= 0) {
    float4 d2 = ((const float4*)selbuf(did2))[row * 64 + lane];
    v[0] += d2.x; v[1] += d2.y; v[2] += d2.z; v[3] += d2.w;
  }
  if (did3 >= 0) {
    float4 d3 = ((const float4*)selbuf(did3))[row * 64 + lane];
    v[0] += d3.x; v[1] += d3.y; v[2] += d3.z; v[3] += d3.w;
  }
  if (did4 >= 0) {
    float4 d4 = ((const float4*)selbuf(did4))[row * 64 + lane];
    v[0] += d4.x; v[1] += d4.y; v[2] += d4.z; v[3] += d4.w;
  }
  float sum = v[0] + v[1] + v[2] + v[3];
  float sq = v[0]*v[0] + v[1]*v[1] + v[2]*v[2] + v[3]*v[3];
  #pragma unroll
  for (int off = 32; off; off >>= 1) {
    sum += __shfl_xor(sum, off);
    sq  += __shfl_xor(sq, off);
  }
  const float mean = sum * (1.f / 256.f);
  const float var = sq * (1.f / 256.f) - mean * mean;
  const float rs = rsqrtf(var + 1e-5f);
  float4 gg = ((const float4*)g)[lane];
  float4 bb = ((const float4*)beta)[lane];
  float4 ov;
  ov.x = (v[0] - mean) * rs * gg.x + bb.x;
  ov.y = (v[1] - mean) * rs * gg.y + bb.y;
  ov.z = (v[2] - mean) * rs * gg.z + bb.z;
  ov.w = (v[3] - mean) * rs * gg.w + bb.w;
  ((float4*)g_x)[row * 64 + lane] = ov;
  short4v sv;
  sv[0] = (short)f2b(ov.x); sv[1] = (short)f2b(ov.y);
  sv[2] = (short)f2b(ov.z); sv[3] = (short)f2b(ov.w);
  *(short4v*)&g_xb[(row * 64 + lane) * 4] = sv;
  if (do_pos) {
    float4 pv = ((const float4*)g_pos)[row * 64 + lane];
    short4v qv;
    qv[0] = (short)f2b(ov.x + pv.x); qv[1] = (short)f2b(ov.y + pv.y);
    qv[2] = (short)f2b(ov.z + pv.z); qv[3] = (short)f2b(ov.w + pv.w);
    *(short4v*)&g_qkb[(row * 64 + lane) * 4] = qv;
  }
}

// ---------------------------------------------------------------------------
extern "C" void kernel_launch(void* const* d_in, const int* in_sizes, int n_in,
                              void* d_out, int out_size, void* d_ws, size_t ws_size,
                              hipStream_t stream) {
  const float* src  = (const float*)d_in[0];
  const float* pose = (const float*)d_in[1];
  const float* Wq   = (const float*)d_in[2];
  const float* Wk   = (const float*)d_in[3];
  const float* Wv   = (const float*)d_in[4];
  const float* Wo   = (const float*)d_in[5];
  const float* bo   = (const float*)d_in[6];
  const float* cw   = (const float*)d_in[7];
  const float* cb   = (const float*)d_in[8];
  const float* nk   = (const float*)d_in[9];
  const float* nv   = (const float*)d_in[10];
  const float* ln1g = (const float*)d_in[11];
  const float* ln1b = (const float*)d_in[12];
  const float* ln2g = (const float*)d_in[13];
  const float* ln2b = (const float*)d_in[14];
  const float* W1   = (const float*)d_in[15];
  const float* b1   = (const float*)d_in[16];
  const float* W2   = (const float*)d_in[17];
  const float* b2   = (const float*)d_in[18];

  const int MT = Bsz * Tt;        // 16000
  const dim3 tgrid(Tt / 32, Dm / 32, Bsz);

  // g_wb layout: per-layer [Wk|Wq] at l*131072; then Wv, Wo, W1, W2.
  const int OV = 262144, OO = 393216, O1 = 524288, O2 = 1572864;
  wconv_all_k<<<10240, 256, 0, stream>>>(Wk, Wq, Wv, Wo, W1, W2);
  trans_in2_k<<<tgrid, 256, 0, stream>>>(src, pose);  // x, xb, pos, qkb

  const int MB = MT / 128;  // 125 m-blocks
  for (int l = 0; l < 2; ++l) {
    const float* bo_l = bo + (size_t)l * Dm;
    const float* cw_l = cw + (size_t)l * Dm * 64;
    const float* cb_l = cb + (size_t)l * Dm;
    const float* nk_l = nk + (size_t)l * Bsz * Dm;
    const float* nv_l = nv + (size_t)l * Bsz * Dm;
    const float* b1_l = b1 + (size_t)l * FFd;
    const float* b2_l = b2 + (size_t)l * Dm;
    const int wkq = l * 131072;
    const int wv = OV + l * 65536, wo = OO + l * 65536;
    const int w1 = O1 + l * 524288, w2 = O2 + l * 524288;

    // [k|q] = qkb @ [Wk|Wq]^T : k -> tb, q -> qb (DUAL, NB=8, grid 1000)
    gemm2_k<64, true, false, false, false, true><<<8 * MB, 256, 0, stream>>>(
        1, wkq, nullptr, 2, 4, 8, MT, 512, Dm);
    // v = xb @ Wv^T -> ffh (scratch)  (NB=4, grid 500)
    gemm2_k<64, false, false, false, false, true><<<4 * MB, 256, 0, stream>>>(
        0, wv, nullptr, 3, 3, 4, MT, Dm, Dm);
    // compress K (tb->kc) and V (ffh->vc) in one dispatch
    compress2_k<<<dim3(50, Bsz, 2), 256, 0, stream>>>(cw_l, cb_l, nk_l, nv_l);
    // kvm = (1/16) kc^T vc
    kvout1_k<<<dim3(Bsz * Hh, JCH), 256, 0, stream>>>();
    kvout2_k<<<Bsz * Hh, 256, 0, stream>>>();
    // W' = kvm (×) Wo  (per-b fused attn+Wo weights)
    wo2_k<<<dim3(Dm, Bsz), 256, 0, stream>>>(wo);
    // t = qb @ W'^T + bo (fp32, per-b, PERB; grid 520)
    gemm2_k<64, false, true, false, true, false><<<Bsz * 13 * 4, 256, 0, stream>>>(
        4, 0, bo_l, 2, 2, 4, MT, Dm, Dm);
    ln_k<<<MT / 4, 256, 0, stream>>>(2, -1, -1, -1,
                                     ln1g + l * Dm, ln1b + l * Dm, 0);

    // Fused FF v4: 4 hidden quarters -> g_qk(+b2), g_t, ffh0, ffh1 [grid 500]
    gemmf_k<<<500, 512, 0, stream>>>(0, w1, w2, b1_l, b2_l);
    // LN2 sums all 4 FF quarters; layer 0 fused with next layer's pos-add.
    ln_k<<<MT / 4, 256, 0, stream>>>(1, 2, 6, 7,
                                     ln2g + l * Dm, ln2b + l * Dm,
                                     l == 0 ? 1 : 0);
  }

  trans_out_k<<<tgrid, 256, 0, stream>>>((float*)d_out);
}

// Round 11
// 334.056 us; speedup vs baseline: 1.5323x; 1.0839x over previous
//
#include <hip/hip_runtime.h>
#include <math.h>

typedef __attribute__((ext_vector_type(8))) short short8;   // 8 bf16
typedef __attribute__((ext_vector_type(4))) short short4v;  // 4 bf16
typedef __attribute__((ext_vector_type(4))) float f32x4;
typedef unsigned int u32;

constexpr int Bsz = 10;
constexpr int Dm  = 256;
constexpr int Hh  = 8;
constexpr int Tt  = 1600;
constexpr int FFd = 2048;
constexpr int Tkv = 802;   // 1 null + 801 compressed
constexpr int JCH = 8;     // j-splits for kv reduction
constexpr size_t Fsz  = (size_t)Bsz * Tt * Dm;    // 4,096,000
constexpr size_t PAD  = 65536;
constexpr size_t KVsz = (size_t)Bsz * Tkv * Dm;   // 2,053,120
constexpr size_t FHsz = (size_t)Bsz * Tt * FFd;   // 32,768,000
constexpr size_t WBsz = 2621440;                  // all weights, bf16

// Static device scratch; referenced ONLY from device code.
__device__ float g_x[Fsz];                        // residual stream fp32
__device__ float g_qk[Fsz];                       // FF half0 out (LN2 d1)
__device__ float g_t[Fsz];                        // Wo out / FF half1 (LN2 d2)
__device__ float g_kc[KVsz];                      // compressed K
__device__ float g_vc[KVsz];                      // compressed V
__device__ float g_kvm[(size_t)Bsz * Hh * 32 * 32];
__device__ float g_kvp[(size_t)JCH * Bsz * Hh * 32 * 32];
__device__ float g_pos[Fsz];                      // transposed pos fp32
__device__ unsigned short g_xb[Fsz + PAD];        // bf16 shadow of x
__device__ unsigned short g_qkb[Fsz + PAD];       // bf16 x+pos
__device__ unsigned short g_tb[Fsz + PAD];        // bf16 k projection
__device__ unsigned short g_qb[Fsz + PAD];        // bf16 q projection
__device__ __attribute__((aligned(16))) unsigned short g_ffh[FHsz + PAD]; // v proj
__device__ unsigned short g_wb[WBsz];             // bf16 weights
__device__ unsigned short g_wo2[(size_t)Bsz * Dm * Dm];  // per-b fused kvm*Wo

__device__ __forceinline__ float* selbuf(int id) {
  switch (id) {
    case 0: return g_x;
    case 1: return g_qk;
    case 2: return g_t;
    case 3: return g_kc;
    case 4: return g_vc;
    case 5: return g_kvm;
    case 6: return (float*)g_ffh;
    default: return (float*)g_ffh + Fsz;
  }
}
__device__ __forceinline__ unsigned short* selbufb(int id) {
  switch (id) {
    case 0: return g_xb;
    case 1: return g_qkb;
    case 2: return g_tb;
    case 3: return g_ffh;
    default: return g_qb;
  }
}

// fp32 -> bf16 (RNE)
__device__ __forceinline__ unsigned short f2b(float x) {
  unsigned int u = __float_as_uint(x);
  u += 0x7FFFu + ((u >> 16) & 1u);
  return (unsigned short)(u >> 16);
}
__device__ __forceinline__ float b2f(unsigned short u) {
  return __uint_as_float(((unsigned int)u) << 16);
}

// ---------------------------------------------------------------------------
// ALL weight conversions in one dispatch. g_wb layout:
// [l0:Wk|Wq][l1:Wk|Wq] | Wv(l0,l1) | Wo(l0,l1) | W1(l0,l1) | W2(l0,l1)
__global__ __launch_bounds__(256) void wconv_all_k(
    const float* __restrict__ Wk, const float* __restrict__ Wq,
    const float* __restrict__ Wv, const float* __restrict__ Wo,
    const float* __restrict__ W1, const float* __restrict__ W2) {
  const int i = blockIdx.x * 256 + threadIdx.x;   // < 2,621,440
  float v;
  if (i < 262144) {
    const int l = i >> 17, r = i & 131071;
    v = (r < 65536) ? Wk[l * 65536 + r] : Wq[l * 65536 + (r - 65536)];
  } else if (i < 393216) {
    v = Wv[i - 262144];
  } else if (i < 524288) {
    v = Wo[i - 393216];
  } else if (i < 1572864) {
    v = W1[i - 524288];
  } else {
    v = W2[i - 1572864];
  }
  g_wb[i] = f2b(v);
}

// ---------------------------------------------------------------------------
// Fused input transpose + pos-add: src,pose [B,D,T] -> g_x, g_xb, g_pos,
// g_qkb = bf16(x+pos).
__global__ __launch_bounds__(256) void trans_in2_k(const float* __restrict__ src,
                                                   const float* __restrict__ pose) {
  __shared__ float ts[32][33];
  __shared__ float tp[32][33];
  const int tx = threadIdx.x & 31, ty = threadIdx.x >> 5;
  const int t0 = blockIdx.x * 32, d0 = blockIdx.y * 32, b = blockIdx.z;
  #pragma unroll
  for (int i = ty; i < 32; i += 8) {
    const size_t gi = ((size_t)(b * Dm + d0 + i)) * Tt + t0 + tx;
    ts[i][tx] = src[gi];
    tp[i][tx] = pose[gi];
  }
  __syncthreads();
  #pragma unroll
  for (int i = ty; i < 32; i += 8) {
    const size_t idx = ((size_t)(b * Tt + t0 + i)) * Dm + d0 + tx;
    const float s = ts[tx][i], p = tp[tx][i];
    g_x[idx] = s;
    g_pos[idx] = p;
    g_xb[idx] = f2b(s);
    g_qkb[idx] = f2b(s + p);
  }
}

__global__ __launch_bounds__(256) void trans_out_k(float* out) {
  __shared__ float tile[32][33];
  const int tx = threadIdx.x & 31, ty = threadIdx.x >> 5;
  const int t0 = blockIdx.x * 32, d0 = blockIdx.y * 32, b = blockIdx.z;
  #pragma unroll
  for (int i = ty; i < 32; i += 8)
    tile[i][tx] = g_x[((size_t)(b * Tt + t0 + i)) * Dm + d0 + tx];
  __syncthreads();
  #pragma unroll
  for (int i = ty; i < 32; i += 8)
    out[((size_t)(b * Dm + d0 + i)) * Tt + t0 + tx] = tile[tx][i];
}

// ---------------------------------------------------------------------------
// MFMA GEMM for K=256 mid-size-grid cases (KQ, V, attn-out): BM=128, BN=64,
// BK=64; 4 waves (2x2). 3 LDS buffers, ONE barrier per K-step, stage
// hoisted before compute (round-4 structure). LDS 72KB -> 2 blocks/CU.
// DUAL (N=512 merged KQ): n0<256 -> Cid, n0>=256 -> C2id, stride 256.
// PERB: per-batch weights g_wo2 (13 m-blocks x NB per b), guarded stores.
template<int BN, bool DUAL, bool PERB, bool RELU, bool BIAS, bool CBF16>
__global__ __launch_bounds__(256) void gemm2_k(
    int Aid, int woff, const float* __restrict__ bias, int Cid, int C2id,
    int NB, int M, int N, int K) {
  constexpr int BM = 128, BK = 64;
  constexpr int ACH = BM * 8;           // 1024 short8 (16 KB)
  constexpr int BCH = BN * 8;           // 512 short8 (8 KB)
  constexpr int NW = BN / 32;           // n-frags per wave
  __shared__ short8 As8[3][ACH];
  __shared__ short8 Bs8[3][BCH];
  const int tid = threadIdx.x;
  const int lane = tid & 63, wid = tid >> 6;
  const int wr = wid >> 1, wc = wid & 1;

  // XCD-aware bijective remap (m204).
  const int nwg = gridDim.x;
  const int bid = blockIdx.x;
  const int q = nwg >> 3, r = nwg & 7;
  const int xcd = bid & 7, seq = bid >> 3;
  const int wgid = (xcd < r ? xcd * (q + 1) : r * (q + 1) + (xcd - r) * q) + seq;

  int m0, n0, mlim;
  const unsigned short* W16;
  if constexpr (PERB) {
    const int per = 13 * NB;
    const int b = wgid / per;
    const int rem = wgid - b * per;
    m0 = b * Tt + (rem / NB) * BM;
    n0 = (rem % NB) * BN;
    mlim = b * Tt + Tt;
    W16 = g_wo2 + (size_t)b * 65536;
  } else {
    m0 = (wgid / NB) * BM;
    n0 = (wgid % NB) * BN;
    mlim = M;
    W16 = g_wb + woff;
  }

  const unsigned short* A16 = selbufb(Aid);
  const bool second = DUAL && (n0 >= 256);
  float* Cf = selbuf(second ? C2id : Cid);
  unsigned short* C16 = selbufb(second ? C2id : Cid);
  const int gn0 = second ? n0 - 256 : n0;
  const int cstride = DUAL ? 256 : N;

  f32x4 acc[4][NW];
  #pragma unroll
  for (int m = 0; m < 4; ++m)
    #pragma unroll
    for (int n = 0; n < NW; ++n) acc[m][n] = (f32x4){0.f, 0.f, 0.f, 0.f};

  const int lkc = lane >> 4, lrc = lane & 15;

  auto stage = [&](int t, int buf) {
    const int k0 = t * BK;
    #pragma unroll
    for (int i = 0; i < ACH / 256; ++i) {
      const int c = tid + i * 256;
      const int row = c >> 3, kc = c & 7;
      const unsigned short* gs = A16 + (size_t)(m0 + row) * K + k0 +
                                 ((kc ^ (row & 7)) << 3);
      __builtin_amdgcn_global_load_lds(
          (const __attribute__((address_space(1))) u32*)gs,
          (__attribute__((address_space(3))) u32*)&As8[buf][c], 16, 0, 0);
    }
    #pragma unroll
    for (int i = 0; i < BCH / 256; ++i) {
      const int c = tid + i * 256;
      const int row = c >> 3, kc = c & 7;
      const unsigned short* gs = W16 + (size_t)(n0 + row) * K + k0 +
                                 ((kc ^ (row & 7)) << 3);
      __builtin_amdgcn_global_load_lds(
          (const __attribute__((address_space(1))) u32*)gs,
          (__attribute__((address_space(3))) u32*)&Bs8[buf][c], 16, 0, 0);
    }
  };

  const int nt = K / BK;
  stage(0, 0);
  if (nt > 1) stage(1, 1);
  int cur = 0, nxt = 2;                 // nxt = (t+2)%3 target
  for (int t = 0; t < nt; ++t) {
    if (t + 1 < nt) {
      asm volatile("s_waitcnt vmcnt(6)" ::: "memory");
    } else {
      asm volatile("s_waitcnt vmcnt(0)" ::: "memory");
    }
    __builtin_amdgcn_sched_barrier(0);
    __builtin_amdgcn_s_barrier();       // buf[cur] landed for ALL waves;
                                        // ALL waves done reading buf[nxt]
    __builtin_amdgcn_sched_barrier(0);
    if (t + 2 < nt) stage(t + 2, nxt);  // overlaps with compute below
    #pragma unroll
    for (int kk = 0; kk < 2; ++kk) {
      short8 af[4], bf[NW];
      #pragma unroll
      for (int m = 0; m < 4; ++m) {
        const int r2 = wr * 64 + m * 16 + lrc;
        af[m] = As8[cur][r2 * 8 + ((kk * 4 + lkc) ^ (r2 & 7))];
      }
      #pragma unroll
      for (int n = 0; n < NW; ++n) {
        const int cn = wc * (BN / 2) + n * 16 + lrc;
        bf[n] = Bs8[cur][cn * 8 + ((kk * 4 + lkc) ^ (cn & 7))];
      }
      #pragma unroll
      for (int m = 0; m < 4; ++m)
        #pragma unroll
        for (int n = 0; n < NW; ++n)
          acc[m][n] = __builtin_amdgcn_mfma_f32_16x16x32_bf16(
              af[m], bf[n], acc[m][n], 0, 0, 0);
    }
    cur = (cur == 2) ? 0 : cur + 1;
    nxt = (nxt == 2) ? 0 : nxt + 1;
  }

  // ---- LDS-staged epilogue: deposit acc, then coalesced row stores ----
  constexpr int CSTR = (BN == 64) ? BN + 4 : BN;
  float* ldsC = (float*)&As8[0][0];
  {
    asm volatile("s_waitcnt vmcnt(0)" ::: "memory");
    __builtin_amdgcn_s_barrier();       // all waves done reading As8/Bs8
    const int r0 = lkc * 4;
    #pragma unroll
    for (int m = 0; m < 4; ++m)
      #pragma unroll
      for (int n = 0; n < NW; ++n) {
        const int col = wc * (BN / 2) + n * 16 + lrc;
        #pragma unroll
        for (int j = 0; j < 4; ++j)
          ldsC[(wr * 64 + m * 16 + r0 + j) * CSTR + col] = acc[m][n][j];
      }
    __syncthreads();
  }
  if constexpr (CBF16) {
    constexpr int CH = BM * BN / 8;     // short8 chunks
    #pragma unroll
    for (int i = 0; i < CH / 256; ++i) {
      const int c = tid + i * 256;
      const int rowl = c / (BN / 8), col8 = (c % (BN / 8)) * 8;
      if (PERB && m0 + rowl >= mlim) continue;
      short8 v;
      #pragma unroll
      for (int j = 0; j < 8; ++j) {
        float x = ldsC[rowl * CSTR + col8 + j];
        if (BIAS) x += bias[gn0 + col8 + j];
        if (RELU) x = fmaxf(x, 0.f);
        v[j] = (short)f2b(x);
      }
      *(short8*)(C16 + (size_t)(m0 + rowl) * cstride + gn0 + col8) = v;
    }
  } else {
    constexpr int CH = BM * BN / 4;     // float4 chunks
    #pragma unroll
    for (int i = 0; i < CH / 256; ++i) {
      const int c = tid + i * 256;
      const int rowl = c / (BN / 4), col4 = (c % (BN / 4)) * 4;
      if (PERB && m0 + rowl >= mlim) continue;
      float4 v;
      float* pv = &v.x;
      #pragma unroll
      for (int j = 0; j < 4; ++j) {
        float x = ldsC[rowl * CSTR + col4 + j];
        if (BIAS) x += bias[gn0 + col4 + j];
        if (RELU) x = fmaxf(x, 0.f);
        pv[j] = x;
      }
      *(float4*)(Cf + (size_t)(m0 + rowl) * cstride + gn0 + col4) = v;
    }
  }
}

// ---------------------------------------------------------------------------
// FUSED FF v5 (round-11): 16-WAVE single block (1024 threads).
// r10 lesson: 2 blocks/CU is unreachable -- unified reg total (VGPR 96 +
// acc AGPRs 64 + areg) ~160 > 128 caps residency at one 8-wave block
// (Occupancy pinned ~20% at grid 250 AND 500; r8's (512,4) spill confirms
// the 128 budget). v5 gets the same latency-hiding INTRA-block: 16 waves =
// 4 waves/SIMD, and per-wave state halves (GEMM1 8Mx2N: areg[8]=32 regs;
// GEMM2 4Mx4N, 32x64 tile: acc2[2][4]=32 AGPRs; total ~110 <= 128, no
// forced spill expected -- FETCH is the spill tripwire).
// Half-split grid 250, NCH=32; half0 -> g_qk (+b2), half1 -> g_t.
__global__ __launch_bounds__(1024, 1) void gemmf_k(
    int Aid, int w1off, int w2off, const float* __restrict__ b1p,
    const float* __restrict__ b2p) {
  constexpr int BM = 128, NCH = 32;     // 32 chunks x 32 hidden = 1024
  __shared__ short8 ws[4096];           // 64 KB: A (prologue) then W dbuf:
                                        // [buf*2048 + w1c:1024 | w2c:1024]
  __shared__ short8 h8[512];            // 8 KB: h 128x32 bf16 (swizzled)
  __shared__ float b1f[1024];           // 4 KB
  const int tid = threadIdx.x;
  const int lane = tid & 63, wid = tid >> 6;     // 16 waves
  const int lkc = lane >> 4, lrc = lane & 15;
  const int nwg = gridDim.x, bid = blockIdx.x;
  const int q = nwg >> 3, r = nwg & 7;
  const int xcd = bid & 7, seq = bid >> 3;
  const int wgid = (xcd < r ? xcd * (q + 1) : r * (q + 1) + (xcd - r) * q) + seq;
  const int half = (wgid >= 125) ? 1 : 0;
  const int m0 = (wgid - half * 125) * BM;
  const int hb = half * 1024;           // hidden base
  const unsigned short* A16 = selbufb(Aid);
  const unsigned short* W1p = g_wb + w1off;
  const unsigned short* W2p = g_wb + w2off;
  float* Cf = half ? g_t : g_qk;

  // ---- prologue: stage A (4/thr) + b1 (1/thr) into LDS ----
  #pragma unroll
  for (int i = 0; i < 4; ++i) {
    const int c = tid + i * 1024;
    const int row = c >> 5, kc = c & 31;
    const unsigned short* gs = A16 + (size_t)(m0 + row) * 256 +
                               ((kc ^ (row & 31)) << 3);
    __builtin_amdgcn_global_load_lds(
        (const __attribute__((address_space(1))) u32*)gs,
        (__attribute__((address_space(3))) u32*)&ws[c], 16, 0, 0);
  }
  __builtin_amdgcn_global_load_lds(
      (const __attribute__((address_space(1))) u32*)(b1p + hb + tid),
      (__attribute__((address_space(3))) u32*)&b1f[tid], 4, 0, 0);
  asm volatile("s_waitcnt vmcnt(0)" ::: "memory");
  __builtin_amdgcn_sched_barrier(0);
  __builtin_amdgcn_s_barrier();

  // ---- hoist this wave's A fragments (16 rows) into registers ----
  const int mg = wid >> 1, ng = wid & 1;         // GEMM1: 8M(16r) x 2N(16c)
  short8 areg[8];
  #pragma unroll
  for (int s = 0; s < 8; ++s) {
    const int r2 = mg * 16 + lrc;
    areg[s] = ws[r2 * 32 + ((s * 4 + lkc) ^ (r2 & 31))];
  }
  asm volatile("s_waitcnt lgkmcnt(0)" ::: "memory");
  __builtin_amdgcn_sched_barrier(0);
  __builtin_amdgcn_s_barrier();         // all waves done reading A from ws

  auto stage_w = [&](int ch, int buf) {
    const int kb = hb + ch * 32;
    {                                   // W1c: 32 rows x 256 k (1/thread)
      const int c = tid;
      const int row = c >> 5, kc = c & 31;
      const unsigned short* gs = W1p + (size_t)(kb + row) * 256 +
                                 ((kc ^ (row & 31)) << 3);
      __builtin_amdgcn_global_load_lds(
          (const __attribute__((address_space(1))) u32*)gs,
          (__attribute__((address_space(3))) u32*)&ws[buf * 2048 + c], 16, 0, 0);
    }
    {                                   // W2c: 256 rows x 32 k (1/thread)
      const int c = tid;
      const int row = c >> 2, kc = c & 3;
      const int g = (kc ^ (row & 3) ^ ((row >> 2) & 3)) & 3;
      const unsigned short* gs = W2p + (size_t)row * 2048 + kb + (g << 3);
      __builtin_amdgcn_global_load_lds(
          (const __attribute__((address_space(1))) u32*)gs,
          (__attribute__((address_space(3))) u32*)&ws[buf * 2048 + 1024 + c],
          16, 0, 0);
    }
  };
  stage_w(0, 0);

  const int wr = wid >> 2, wc = wid & 3;         // GEMM2: 4x4 waves, 32x64
  f32x4 acc2[2][4];
  #pragma unroll
  for (int m = 0; m < 2; ++m)
    #pragma unroll
    for (int n = 0; n < 4; ++n) acc2[m][n] = (f32x4){0.f, 0.f, 0.f, 0.f};

  for (int ch = 0; ch < NCH; ++ch) {
    const int cur = ch & 1;
    const int wb = cur * 2048;
    asm volatile("s_waitcnt vmcnt(0)" ::: "memory");   // W(ch) landed (mine)
    __builtin_amdgcn_sched_barrier(0);
    __builtin_amdgcn_s_barrier();       // barrier A: W(ch) landed for ALL;
                                        // GEMM1/2(ch-1) reads of buf^1 done
    __builtin_amdgcn_sched_barrier(0);
    if (ch + 1 < NCH) stage_w(ch + 1, cur ^ 1);

    // ---- GEMM1: h = relu(A @ W1c^T + b1); A from regs, 8 bf reads ----
    f32x4 a1 = (f32x4){0.f, 0.f, 0.f, 0.f};
    const int cn1 = ng * 16 + lrc;
    #pragma unroll
    for (int s = 0; s < 8; ++s) {
      short8 bf = ws[wb + cn1 * 32 + ((s * 4 + lkc) ^ cn1)];
      a1 = __builtin_amdgcn_mfma_f32_16x16x32_bf16(areg[s], bf, a1, 0, 0, 0);
    }
    // bias + relu + bf16 -> h LDS (swizzled for GEMM2 reads)
    unsigned short* h16 = (unsigned short*)h8;
    #pragma unroll
    for (int j = 0; j < 4; ++j) {
      const int row = mg * 16 + lkc * 4 + j;
      const float v = fmaxf(a1[j] + b1f[ch * 32 + cn1], 0.f);
      const int g = ((cn1 >> 3) ^ (row & 3) ^ ((row >> 2) & 3)) & 3;
      h16[row * 32 + g * 8 + (cn1 & 7)] = f2b(v);
    }
    asm volatile("s_waitcnt lgkmcnt(0)" ::: "memory");
    __builtin_amdgcn_sched_barrier(0);
    __builtin_amdgcn_s_barrier();       // barrier B: h visible to all waves
    __builtin_amdgcn_sched_barrier(0);

    // ---- GEMM2: acc2 += h @ W2c^T (K=32) ----
    short8 af2[2], bf2[4];
    #pragma unroll
    for (int m = 0; m < 2; ++m) {
      const int r2 = wr * 32 + m * 16 + lrc;
      af2[m] = h8[r2 * 4 + ((lkc ^ (r2 & 3) ^ ((r2 >> 2) & 3)) & 3)];
    }
    #pragma unroll
    for (int n = 0; n < 4; ++n) {
      const int cn = wc * 64 + n * 16 + lrc;
      bf2[n] = ws[wb + 1024 + cn * 4 + ((lkc ^ (cn & 3) ^ ((cn >> 2) & 3)) & 3)];
    }
    #pragma unroll
    for (int m = 0; m < 2; ++m)
      #pragma unroll
      for (int n = 0; n < 4; ++n)
        acc2[m][n] = __builtin_amdgcn_mfma_f32_16x16x32_bf16(
            af2[m], bf2[n], acc2[m][n], 0, 0, 0);
  }

  // ---- direct fp32 epilogue (half 0 adds b2) ----
  const int r0 = lkc * 4;
  #pragma unroll
  for (int m = 0; m < 2; ++m) {
    const int gm = m0 + wr * 32 + m * 16 + r0;
    #pragma unroll
    for (int n = 0; n < 4; ++n) {
      const int gn = wc * 64 + n * 16 + lrc;
      const float bb = (half == 0) ? b2p[gn] : 0.f;
      #pragma unroll
      for (int j = 0; j < 4; ++j)
        Cf[(size_t)(gm + j) * 256 + gn] = acc2[m][n][j] + bb;
    }
  }
}

// ---------------------------------------------------------------------------
// Conv compression, K and V in one dispatch (blockIdx.z): z=0 reads g_tb
// (k proj) -> g_kc with null_k edge; z=1 reads g_ffh (v proj) -> g_vc.
__global__ __launch_bounds__(256) void compress2_k(
    const float* __restrict__ cw, const float* __restrict__ cb,
    const float* __restrict__ nk, const float* __restrict__ nv) {
  __shared__ float rows[32][256];       // 32 KB
  const int tc0 = 1 + blockIdx.x * 16;
  const int b = blockIdx.y;
  const int z = blockIdx.z;
  const int tid = threadIdx.x;
  const int o = tid;
  const int g = o >> 5;

  const unsigned short* srcbuf = z ? g_ffh : g_tb;
  const float* nul = z ? nv : nk;
  float* outb = (z ? g_vc : g_kc) + (size_t)b * Tkv * Dm;

  const int r0g = 2 * tc0 - 2;
  const unsigned short* src = srcbuf + ((size_t)b * Tt + r0g) * Dm;
  #pragma unroll
  for (int i = 0; i < 4; ++i) {
    const int c = tid + i * 256;        // 1024 chunks of 8
    const int row = c >> 5, off = (c & 31) * 8;
    short8 v = *(const short8*)(src + (size_t)row * 256 + off);
    #pragma unroll
    for (int j = 0; j < 8; ++j)
      rows[row][off + j] = b2f((unsigned short)v[j]);
  }

  float we[32], wo[32];
  {
    const float4* wp = (const float4*)(cw + o * 64);
    #pragma unroll
    for (int i = 0; i < 16; ++i) {
      float4 w4 = wp[i];
      we[i * 2 + 0] = w4.x; wo[i * 2 + 0] = w4.y;
      we[i * 2 + 1] = w4.z; wo[i * 2 + 1] = w4.w;
    }
  }
  const float bias = cb[o];
  if (blockIdx.x == 0) {                // edge rows j=0,1
    outb[o] = nul[b * Dm + o];
    outb[Dm + o] = bias;
  }
  __syncthreads();

  float* outp = outb + o;
  #pragma unroll
  for (int t = 0; t < 16; ++t) {
    const int lr = 2 * t;
    const float* p0 = &rows[lr][g * 32];
    const float* p1 = &rows[lr + 1][g * 32];
    float acc = bias;
    #pragma unroll
    for (int i4 = 0; i4 < 8; ++i4) {
      float4 a0 = *(const float4*)(p0 + i4 * 4);
      float4 a1 = *(const float4*)(p1 + i4 * 4);
      acc = fmaf(we[i4 * 4 + 0], a0.x, acc);
      acc = fmaf(we[i4 * 4 + 1], a0.y, acc);
      acc = fmaf(we[i4 * 4 + 2], a0.z, acc);
      acc = fmaf(we[i4 * 4 + 3], a0.w, acc);
      acc = fmaf(wo[i4 * 4 + 0], a1.x, acc);
      acc = fmaf(wo[i4 * 4 + 1], a1.y, acc);
      acc = fmaf(wo[i4 * 4 + 2], a1.z, acc);
      acc = fmaf(wo[i4 * 4 + 3], a1.w, acc);
    }
    outp[(size_t)(1 + tc0 + t) * Dm] = acc;
  }
}

// ---------------------------------------------------------------------------
// KV reduction stage 1/2 (validated).
__global__ __launch_bounds__(256) void kvout1_k() {
  __shared__ float kl[8][32];
  __shared__ float vl[8][32];
  const int bh = blockIdx.x;
  const int js = blockIdx.y;
  const int b = bh >> 3, h = bh & 7;
  const int j0 = js * 101;
  const int jend = (j0 + 101 < Tkv) ? j0 + 101 : Tkv;

  const int tid = threadIdx.x;
  const int lr = tid >> 5;
  const int lc = tid & 31;
  const int e = tid >> 3;
  const int d0 = (tid & 7) * 4;

  float a0 = 0.f, a1 = 0.f, a2 = 0.f, a3 = 0.f;
  const size_t base = (size_t)b * Tkv * Dm + h * 32;

  for (int jc = j0; jc < jend; jc += 8) {
    const int jr = jc + lr;
    if (jr < jend) {
      kl[lr][lc] = g_kc[base + (size_t)jr * Dm + lc];
      vl[lr][lc] = g_vc[base + (size_t)jr * Dm + lc];
    } else {
      kl[lr][lc] = 0.f;
      vl[lr][lc] = 0.f;
    }
    __syncthreads();
    #pragma unroll
    for (int r = 0; r < 8; ++r) {
      const float kf = kl[r][e];
      const float* vr = &vl[r][d0];
      a0 = fmaf(kf, vr[0], a0);
      a1 = fmaf(kf, vr[1], a1);
      a2 = fmaf(kf, vr[2], a2);
      a3 = fmaf(kf, vr[3], a3);
    }
    __syncthreads();
  }
  float* op = g_kvp + ((size_t)js * 80 + bh) * 1024 + e * 32 + d0;
  op[0] = a0; op[1] = a1; op[2] = a2; op[3] = a3;
}

__global__ __launch_bounds__(256) void kvout2_k() {
  const int bh = blockIdx.x;
  const int tid = threadIdx.x;
  const int e = tid >> 3;
  const int d0 = (tid & 7) * 4;
  float a0 = 0.f, a1 = 0.f, a2 = 0.f, a3 = 0.f;
  #pragma unroll
  for (int s = 0; s < JCH; ++s) {
    const float* p = g_kvp + ((size_t)s * 80 + bh) * 1024 + e * 32 + d0;
    a0 += p[0]; a1 += p[1]; a2 += p[2]; a3 += p[3];
  }
  float* op = g_kvm + (size_t)bh * 1024 + e * 32 + d0;
  op[0] = a0 * 0.0625f;
  op[1] = a1 * 0.0625f;
  op[2] = a2 * 0.0625f;
  op[3] = a3 * 0.0625f;
}

// ---------------------------------------------------------------------------
// W'[b,n,h*32+e] = sum_d kvm[b,h,e,d] * Wo[n,h*32+d]   (bf16 out)
__global__ __launch_bounds__(256) void wo2_k(int wooff) {
  const int n = blockIdx.x, b = blockIdx.y;
  const int he = threadIdx.x;
  const int h = he >> 5, e = he & 31;
  const float* kp = g_kvm + ((size_t)(b * Hh + h) * 32 + e) * 32;
  const unsigned short* wp = g_wb + wooff + (size_t)n * Dm + h * 32;
  float acc = 0.f;
  #pragma unroll
  for (int d = 0; d < 32; ++d) acc = fmaf(kp[d], b2f(wp[d]), acc);
  g_wo2[(size_t)b * 65536 + (size_t)n * Dm + he] = f2b(acc);
}

// ---------------------------------------------------------------------------
// x = LN(x + d1 [+ d2 + d3 + d4])*g + beta (fp32), writes bf16 shadow g_xb.
// If do_pos: also writes g_qkb = bf16(ln_out + pos).
__global__ __launch_bounds__(256) void ln_k(int did, int did2, int did3,
                                            int did4, const float* g,
                                            const float* beta, int do_pos) {
  const int lane = threadIdx.x & 63;
  const int wave = threadIdx.x >> 6;
  const size_t row = (size_t)blockIdx.x * 4 + wave;
  float4 xv = ((const float4*)g_x)[row * 64 + lane];
  float4 dv = ((const float4*)selbuf(did))[row * 64 + lane];
  float v[4] = {xv.x + dv.x, xv.y + dv.y, xv.z + dv.z, xv.w + dv.w};
  if (did2 >= 0) {
    float4 d2 = ((const float4*)selbuf(did2))[row * 64 + lane];
    v[0] += d2.x; v[1] += d2.y; v[2] += d2.z; v[3] += d2.w;
  }
  if (did3 >= 0) {
    float4 d3 = ((const float4*)selbuf(did3))[row * 64 + lane];
    v[0] += d3.x; v[1] += d3.y; v[2] += d3.z; v[3] += d3.w;
  }
  if (did4 >= 0) {
    float4 d4 = ((const float4*)selbuf(did4))[row * 64 + lane];
    v[0] += d4.x; v[1] += d4.y; v[2] += d4.z; v[3] += d4.w;
  }
  float sum = v[0] + v[1] + v[2] + v[3];
  float sq = v[0]*v[0] + v[1]*v[1] + v[2]*v[2] + v[3]*v[3];
  #pragma unroll
  for (int off = 32; off; off >>= 1) {
    sum += __shfl_xor(sum, off);
    sq  += __shfl_xor(sq, off);
  }
  const float mean = sum * (1.f / 256.f);
  const float var = sq * (1.f / 256.f) - mean * mean;
  const float rs = rsqrtf(var + 1e-5f);
  float4 gg = ((const float4*)g)[lane];
  float4 bb = ((const float4*)beta)[lane];
  float4 ov;
  ov.x = (v[0] - mean) * rs * gg.x + bb.x;
  ov.y = (v[1] - mean) * rs * gg.y + bb.y;
  ov.z = (v[2] - mean) * rs * gg.z + bb.z;
  ov.w = (v[3] - mean) * rs * gg.w + bb.w;
  ((float4*)g_x)[row * 64 + lane] = ov;
  short4v sv;
  sv[0] = (short)f2b(ov.x); sv[1] = (short)f2b(ov.y);
  sv[2] = (short)f2b(ov.z); sv[3] = (short)f2b(ov.w);
  *(short4v*)&g_xb[(row * 64 + lane) * 4] = sv;
  if (do_pos) {
    float4 pv = ((const float4*)g_pos)[row * 64 + lane];
    short4v qv;
    qv[0] = (short)f2b(ov.x + pv.x); qv[1] = (short)f2b(ov.y + pv.y);
    qv[2] = (short)f2b(ov.z + pv.z); qv[3] = (short)f2b(ov.w + pv.w);
    *(short4v*)&g_qkb[(row * 64 + lane) * 4] = qv;
  }
}

// ---------------------------------------------------------------------------
extern "C" void kernel_launch(void* const* d_in, const int* in_sizes, int n_in,
                              void* d_out, int out_size, void* d_ws, size_t ws_size,
                              hipStream_t stream) {
  const float* src  = (const float*)d_in[0];
  const float* pose = (const float*)d_in[1];
  const float* Wq   = (const float*)d_in[2];
  const float* Wk   = (const float*)d_in[3];
  const float* Wv   = (const float*)d_in[4];
  const float* Wo   = (const float*)d_in[5];
  const float* bo   = (const float*)d_in[6];
  const float* cw   = (const float*)d_in[7];
  const float* cb   = (const float*)d_in[8];
  const float* nk   = (const float*)d_in[9];
  const float* nv   = (const float*)d_in[10];
  const float* ln1g = (const float*)d_in[11];
  const float* ln1b = (const float*)d_in[12];
  const float* ln2g = (const float*)d_in[13];
  const float* ln2b = (const float*)d_in[14];
  const float* W1   = (const float*)d_in[15];
  const float* b1   = (const float*)d_in[16];
  const float* W2   = (const float*)d_in[17];
  const float* b2   = (const float*)d_in[18];

  const int MT = Bsz * Tt;        // 16000
  const dim3 tgrid(Tt / 32, Dm / 32, Bsz);

  // g_wb layout: per-layer [Wk|Wq] at l*131072; then Wv, Wo, W1, W2.
  const int OV = 262144, OO = 393216, O1 = 524288, O2 = 1572864;
  wconv_all_k<<<10240, 256, 0, stream>>>(Wk, Wq, Wv, Wo, W1, W2);
  trans_in2_k<<<tgrid, 256, 0, stream>>>(src, pose);  // x, xb, pos, qkb

  const int MB = MT / 128;  // 125 m-blocks
  for (int l = 0; l < 2; ++l) {
    const float* bo_l = bo + (size_t)l * Dm;
    const float* cw_l = cw + (size_t)l * Dm * 64;
    const float* cb_l = cb + (size_t)l * Dm;
    const float* nk_l = nk + (size_t)l * Bsz * Dm;
    const float* nv_l = nv + (size_t)l * Bsz * Dm;
    const float* b1_l = b1 + (size_t)l * FFd;
    const float* b2_l = b2 + (size_t)l * Dm;
    const int wkq = l * 131072;
    const int wv = OV + l * 65536, wo = OO + l * 65536;
    const int w1 = O1 + l * 524288, w2 = O2 + l * 524288;

    // [k|q] = qkb @ [Wk|Wq]^T : k -> tb, q -> qb (DUAL, NB=8, grid 1000)
    gemm2_k<64, true, false, false, false, true><<<8 * MB, 256, 0, stream>>>(
        1, wkq, nullptr, 2, 4, 8, MT, 512, Dm);
    // v = xb @ Wv^T -> ffh (scratch)  (NB=4, grid 500)
    gemm2_k<64, false, false, false, false, true><<<4 * MB, 256, 0, stream>>>(
        0, wv, nullptr, 3, 3, 4, MT, Dm, Dm);
    // compress K (tb->kc) and V (ffh->vc) in one dispatch
    compress2_k<<<dim3(50, Bsz, 2), 256, 0, stream>>>(cw_l, cb_l, nk_l, nv_l);
    // kvm = (1/16) kc^T vc
    kvout1_k<<<dim3(Bsz * Hh, JCH), 256, 0, stream>>>();
    kvout2_k<<<Bsz * Hh, 256, 0, stream>>>();
    // W' = kvm (×) Wo  (per-b fused attn+Wo weights)
    wo2_k<<<dim3(Dm, Bsz), 256, 0, stream>>>(wo);
    // t = qb @ W'^T + bo (fp32, per-b, PERB; grid 520)
    gemm2_k<64, false, true, false, true, false><<<Bsz * 13 * 4, 256, 0, stream>>>(
        4, 0, bo_l, 2, 2, 4, MT, Dm, Dm);
    ln_k<<<MT / 4, 256, 0, stream>>>(2, -1, -1, -1,
                                     ln1g + l * Dm, ln1b + l * Dm, 0);

    // Fused FF v5: 16-wave block; half0 -> g_qk (+b2), half1 -> g_t [grid 250]
    gemmf_k<<<250, 1024, 0, stream>>>(0, w1, w2, b1_l, b2_l);
    // LN2 sums both FF halves; layer 0 fused with next layer's pos-add.
    ln_k<<<MT / 4, 256, 0, stream>>>(1, 2, -1, -1,
                                     ln2g + l * Dm, ln2b + l * Dm,
                                     l == 0 ? 1 : 0);
  }

  trans_out_k<<<tgrid, 256, 0, stream>>>((float*)d_out);
}